// Round 12
// baseline (211.960 us; speedup 1.0000x reference)
//
#include <hip/hip_runtime.h>
#include <math.h>

// ---------------------------------------------------------------------------
// SocialLstm: T=24, N=2048, INPUT_DIM=2, HIDDEN=64, MEDIATE=128, SOCIAL=64,
// OUT_DIM=2, N_SIZE=2, CELL=0.3, T_obs=9, T_pred=19, WIN=9.
//
// R12: wave-autonomous social path. The e-columns (64 of 256 K) leave the
// MFMA: g = gbufA(r,h MFMA, 6 kt) + bc + ge, with ge = eW0 const (fp32) for
// unmatched agents or a wave-local fp32 matvec e*Wce for matched ones (Wce
// float4-packed in LDS so matvec output lanes == LSTM gate lanes). The poll
// for h_{t-1} now runs in phase D of step t, one FULL step after the
// producer's phase-D publish (slack = D-rest + bar + C ~ 0.5us -> first-try
// hits), and nothing between poll and use crosses a barrier -> no wave ever
// waits on another wave's poll. 2 lgkm-only barriers/step. Service blocks
// (hash match / We fold / tail zero) fused as in R11; service LDS unioned
// with Wce/Wef (146.9 KiB, 1 block/CU).
// MFMA hi/lo bf16 split for r/h (ZhWh+ZlWh+ZhWl) verified R3-R11; e-path is
// now full fp32 (more accurate than the bf16 e-MFMA it replaces).
// ---------------------------------------------------------------------------

#define N_AG   2048
#define STEPS  20
#define CAP    12
#define NSRV   21
#define MAGIC  0x13572468

typedef short short8 __attribute__((ext_vector_type(8)));
typedef float f32x4  __attribute__((ext_vector_type(4)));
union FU { uint4 q; short8 v; };

__device__ __forceinline__ unsigned short bf16rne(float x) {
    unsigned u = __float_as_uint(x);
    unsigned r = (u + 0x7fff + ((u >> 16) & 1)) >> 16;
    return (unsigned short)r;
}

__device__ __forceinline__ void pack8(const float* v, uint4& hq, uint4& lq) {
    unsigned uh[4], ul[4];
    #pragma unroll
    for (int w = 0; w < 4; w++) {
        float v0 = v[2 * w], v1 = v[2 * w + 1];
        unsigned short h0 = bf16rne(v0), h1 = bf16rne(v1);
        float f0 = __uint_as_float(((unsigned)h0) << 16);
        float f1 = __uint_as_float(((unsigned)h1) << 16);
        unsigned short l0 = bf16rne(v0 - f0), l1 = bf16rne(v1 - f1);
        uh[w] = (unsigned)h0 | ((unsigned)h1 << 16);
        ul[w] = (unsigned)l0 | ((unsigned)l1 << 16);
    }
    hq = make_uint4(uh[0], uh[1], uh[2], uh[3]);
    lq = make_uint4(ul[0], ul[1], ul[2], ul[3]);
}

__device__ __forceinline__ int khash(int k) {
    return (int)(((unsigned)k * 2654435761u) >> 21);   // 11-bit bucket
}

__device__ __forceinline__ float fsigm(float x) {
    return __builtin_amdgcn_rcpf(1.f + __expf(-x));
}
__device__ __forceinline__ float ftanh(float x) {
    float e = __expf(2.f * x);
    return 1.f - 2.f * __builtin_amdgcn_rcpf(e + 1.f);
}

// LDS-only barrier (no vmcnt drain; global exchanges use the tag protocol).
__device__ __forceinline__ void bar_lds() {
    asm volatile("s_waitcnt lgkmcnt(0)\n\ts_barrier" ::: "memory");
}

__device__ __forceinline__ void ast(int* p_, int v) {
    __hip_atomic_store(p_, v, __ATOMIC_RELAXED, __HIP_MEMORY_SCOPE_AGENT);
}
__device__ __forceinline__ void astf(float* p_, float v) {
    __hip_atomic_store(p_, v, __ATOMIC_RELAXED, __HIP_MEMORY_SCOPE_AGENT);
}

struct KP {
    const float *X, *masks, *h_in, *c_in;
    const float *Win, *bin, *Wsoc, *bsoc, *Wih, *Whh, *bih, *bhh, *Wout, *bout;
    float *Wef;
    int *mcnt, *midx, *need, *flags;
    float *out;
    unsigned long long *hist;    // 19 slices x [2048][64] of (tag<<32|f32bits)
};

__global__ __launch_bounds__(512, 2) void k_all(KP p)
{
    // ---- persist LDS ----
    __shared__ __align__(16) uint4 zshq[408];     // 24 groups * 17 (r:0-15, h:16-23)
    __shared__ __align__(16) uint4 zslq[408];
    __shared__ float gbufA[16][258];              // r/h-partial gates
    __shared__ float cvs[16][64];                 // wave-local rows
    __shared__ float es[16][65];                  // wave-local rows
    __shared__ float hs[16][68];                  // wave-local rows
    __shared__ float2 sWinP[16 * 17];
    __shared__ float sBinP[16 * 9];
    __shared__ float sX[11][16][2];
    __shared__ float sMask[STEPS][16];
    __shared__ int   sCnt[STEPS][16];
    __shared__ int   sNeed[19][16];
    __shared__ int   sMidx[STEPS][16][CAP];
    __shared__ float sBsoc[64], sBc[256], sWout[128], sBout[2], sEW0[256];
    // service arrays unioned with the persist Wce/Wef region
    __shared__ union WU {
        struct { float4 Wce4[64 * 64]; float WefP[64 * 65]; } w;
        struct { int kk[N_AG]; int head[N_AG]; int nxt[N_AG]; float red[512]; } s;
    } u;

    const int tid = threadIdx.x;
    const int bxg = blockIdx.x;

    // =====================================================================
    // SERVICE BLOCKS 0..20
    // =====================================================================
    if (bxg < NSRV) {
        const int sb = bxg;
        {   // out-tail zero slice (frames 20..23 = 16384 floats)
            int lo = sb * 780;
            int hi = (sb == NSRV - 1) ? 16384 : lo + 780;
            for (int i = lo + tid; i < hi; i += 512)
                p.out[20 * N_AG * 2 + i] = 0.f;
        }
        if (sb == 20) {           // We fold
            for (int i = tid; i < 4096; i += 512) {
                int s = i >> 6, k = i & 63;
                float a = 0.f;
                #pragma unroll
                for (int w = 0; w < 9; w++) a += p.Wsoc[s * 576 + w * 64 + k];
                astf(&p.Wef[i], a);
            }
            __syncthreads();
            if (tid == 0) ast(&p.flags[20], MAGIC);
            return;
        }

        const int t = sb;
        const float* Xt = p.X + t * N_AG * 2;

        float mnx = 1e30f, mny = 1e30f;
        for (int i = tid; i < N_AG; i += 512) {
            mnx = fminf(mnx, Xt[2 * i]);
            mny = fminf(mny, Xt[2 * i + 1]);
        }
        u.s.red[tid] = mnx; __syncthreads();
        for (int s = 256; s > 0; s >>= 1) { if (tid < s) u.s.red[tid] = fminf(u.s.red[tid], u.s.red[tid + s]); __syncthreads(); }
        float ltx = u.s.red[0]; __syncthreads();
        u.s.red[tid] = mny; __syncthreads();
        for (int s = 256; s > 0; s >>= 1) { if (tid < s) u.s.red[tid] = fminf(u.s.red[tid], u.s.red[tid + s]); __syncthreads(); }
        float lty = u.s.red[0]; __syncthreads();
        ltx -= 1.2f;   // margin = 2*N_SIZE*CELL
        lty -= 1.2f;

        for (int i = tid; i < N_AG; i += 512) {
            float m = p.masks[t * N_AG + i];
            int px = (int)floorf((Xt[2 * i]     - ltx) / 0.3f);
            int py = (int)floorf((Xt[2 * i + 1] - lty) / 0.3f);
            int im = (int)m;
            px *= im; py *= im;
            u.s.kk[i] = px * 65536 + py;   // masked -> 0; real agents px,py >= 4
            u.s.head[i] = -1;
            if (t >= 1) ast(&p.need[(t - 1) * N_AG + i], 0);
        }
        __syncthreads();
        for (int j = tid; j < N_AG; j += 512) {
            int kj = u.s.kk[j];
            if (kj != 0) u.s.nxt[j] = atomicExch(&u.s.head[khash(kj)], j);
        }
        __syncthreads();
        for (int i = tid; i < N_AG; i += 512) {
            int ki = u.s.kk[i];
            int cnt = 0;
            int base = (t * N_AG + i) * CAP;
            if (ki != 0) {
                int tkey = ki - 65537;
                int lst[CAP];
                for (int j = u.s.head[khash(tkey)]; j >= 0; j = u.s.nxt[j]) {
                    if (u.s.kk[j] == tkey) { if (cnt < CAP) lst[cnt] = j; cnt++; }
                }
                if (cnt > CAP) cnt = CAP;
                for (int a = 1; a < cnt; a++) {       // ascending j = ref order
                    int v = lst[a]; int b = a - 1;
                    while (b >= 0 && lst[b] > v) { lst[b + 1] = lst[b]; b--; }
                    lst[b + 1] = v;
                }
                for (int a = 0; a < cnt; a++) {
                    ast(&p.midx[base + a], lst[a]);
                    if (t >= 1) ast(&p.need[(t - 1) * N_AG + lst[a]], 1);
                }
            }
            ast(&p.mcnt[t * N_AG + i], cnt);
        }
        __syncthreads();
        if (tid == 0) ast(&p.flags[t], MAGIC);
        return;
    }

    // =====================================================================
    // PERSIST BLOCKS 21..148
    // =====================================================================
    const int bx    = bxg - NSRV;
    const int wbase = bx * 16;
    const int wv    = tid >> 6, lane = tid & 63;
    const int mA    = lane & 15, quad = lane >> 4;
    const int nt0   = 2 * wv;
    const int m0w   = wv, m1w = wv + 8;           // agents owned by this wave

    // ---- prologue part A (independent of service tables) ----
    if (tid < 256) {
        sBc[tid] = p.bih[tid] + p.bhh[tid];
        float acc = 0.f;                           // eW0[g] = relu(bsoc) . Wce[g]
        const float* wp = p.Wih + tid * 192 + 128;
        for (int k = 0; k < 64; k++) acc += fmaxf(p.bsoc[k], 0.f) * wp[k];
        sEW0[tid] = acc;
    }
    if (tid < 128) {
        sWout[tid] = p.Wout[tid];
        int c = tid;
        sWinP[(c >> 3) * 17 + (c & 7)] = make_float2(p.Win[2 * c], p.Win[2 * c + 1]);
        sBinP[(c >> 3) * 9 + (c & 7)] = p.bin[c];
    }
    if (tid < 64) sBsoc[tid] = p.bsoc[tid];
    if (tid < 2)  sBout[tid] = p.bout[tid];
    if (tid < 352) { int tt = tid / 32, r = tid % 32;
                     sX[tt][r >> 1][r & 1] = p.X[tt * (N_AG * 2) + (wbase + (r >> 1)) * 2 + (r & 1)]; }
    if (tid < 320) { int tt = tid / 16, m2 = tid % 16;
                     sMask[tt][m2] = p.masks[tt * N_AG + wbase + m2]; }
    // Wce float4-packed: Wce4[s][l] = Wc gates {l, l+64, l+128, l+192} at e-col s
    for (int i = tid; i < 4096; i += 512) {
        int s = i >> 6, l = i & 63;
        u.w.Wce4[s * 64 + l] = make_float4(
            p.Wih[l * 192 + 128 + s],         p.Wih[(l + 64) * 192 + 128 + s],
            p.Wih[(l + 128) * 192 + 128 + s], p.Wih[(l + 192) * 192 + 128 + s]);
    }

    // own h (wave-local LDS rows) + c (registers)
    float c0, c1;
    {
        int mm0 = tid >> 6, h0i = tid & 63, mm1 = mm0 + 8;
        hs[mm0][h0i] = p.h_in[(wbase + mm0) * 64 + h0i];
        hs[mm1][h0i] = p.h_in[(wbase + mm1) * 64 + h0i];
        c0 = p.c_in[(wbase + mm0) * 64 + h0i];
        c1 = p.c_in[(wbase + mm1) * 64 + h0i];
    }

    // register-resident W fragments for r/h k-tiles {0,1,2,3,6,7}
    FU wh[2][6], wl[2][6];
    #pragma unroll
    for (int e = 0; e < 2; e++) {
        int g = (nt0 + e) * 16 + mA;
        #pragma unroll
        for (int uix = 0; uix < 6; uix++) {
            int kt = (uix < 4) ? uix : uix + 2;
            int k0 = kt * 32 + quad * 8;          // 8-run never crosses 192
            const float* src = (k0 < 192) ? (p.Wih + g * 192 + k0)
                                          : (p.Whh + g * 64 + (k0 - 192));
            float v[8];
            #pragma unroll
            for (int j = 0; j < 8; j++) v[j] = src[j];
            pack8(v, wh[e][uix].q, wl[e][uix].q);
        }
    }

    // ---- wait for service flags (overlapped with prologue above) ----
    if (tid < NSRV) {
        while (__hip_atomic_load(&p.flags[tid], __ATOMIC_RELAXED,
                                 __HIP_MEMORY_SCOPE_AGENT) != MAGIC) { }
    }
    __syncthreads();

    // ---- prologue part B: service tables + t=0 frag build ----
    if (tid < 320) { int tt = tid / 16, m2 = tid % 16;
                     sCnt[tt][m2] = p.mcnt[tt * N_AG + wbase + m2]; }
    if (tid < 304) { int s = tid / 16, m2 = tid % 16;
                     sNeed[s][m2] = p.need[s * N_AG + wbase + m2]; }
    for (int i = tid; i < 4096; i += 512)
        u.w.WefP[(i >> 6) * 65 + (i & 63)] = p.Wef[i];
    for (int i = tid; i < STEPS * 16 * CAP; i += 512) {
        int tt = i / (16 * CAP), r = i % (16 * CAP), m2 = r / CAP, n = r % CAP;
        sMidx[tt][m2][n] = p.midx[(tt * N_AG + wbase + m2) * CAP + n];
    }
    // t=0 frags (wave-local; hs rows were written by this wave in part A)
    if (lane < 32) {
        int a = lane & 1, s5r = lane >> 1;
        int m = a ? m1w : m0w;
        float px = sX[0][m][0], py = sX[0][m][1];
        float v[8];
        #pragma unroll
        for (int j = 0; j < 8; j++) {
            float2 w2 = sWinP[s5r * 17 + j];
            v[j] = fmaxf(w2.x * px + w2.y * py + sBinP[s5r * 9 + j], 0.f);
        }
        pack8(v, zshq[s5r * 17 + m], zslq[s5r * 17 + m]);
    } else if (lane < 48) {
        int idx = lane - 32, a = idx & 1, s58 = idx >> 1;
        int m = a ? m1w : m0w;
        float v[8];
        #pragma unroll
        for (int j = 0; j < 8; j++) v[j] = hs[m][s58 * 8 + j];
        pack8(v, zshq[(16 + s58) * 17 + m], zslq[(16 + s58) * 17 + m]);
    }
    __syncthreads();

    float op0x = 0.f, op0y = 0.f, op1x = 0.f, op1y = 0.f;   // out of step t-1

    // =================== recurrence: 2 lgkm barriers/step ===================
    #pragma unroll 1
    for (int t = 0; t < STEPS; t++) {
        // ---- C: r/h GEMM (6 k-tiles, 36 MFMA) -> gbufA ----
        {
            f32x4 a0v = {0.f, 0.f, 0.f, 0.f};
            f32x4 a1v = {0.f, 0.f, 0.f, 0.f};
            #pragma unroll
            for (int uix = 0; uix < 6; uix++) {
                int fi = (uix * 4 + quad) * 17 + mA;
                FU az, bz;
                az.q = zshq[fi];
                bz.q = zslq[fi];
                a0v = __builtin_amdgcn_mfma_f32_16x16x32_bf16(az.v, wh[0][uix].v, a0v, 0, 0, 0);
                a1v = __builtin_amdgcn_mfma_f32_16x16x32_bf16(az.v, wh[1][uix].v, a1v, 0, 0, 0);
                a0v = __builtin_amdgcn_mfma_f32_16x16x32_bf16(bz.v, wh[0][uix].v, a0v, 0, 0, 0);
                a1v = __builtin_amdgcn_mfma_f32_16x16x32_bf16(bz.v, wh[1][uix].v, a1v, 0, 0, 0);
                a0v = __builtin_amdgcn_mfma_f32_16x16x32_bf16(az.v, wl[0][uix].v, a0v, 0, 0, 0);
                a1v = __builtin_amdgcn_mfma_f32_16x16x32_bf16(az.v, wl[1][uix].v, a1v, 0, 0, 0);
            }
            #pragma unroll
            for (int r = 0; r < 4; r++) {
                int row = quad * 4 + r;
                gbufA[row][nt0 * 16 + mA]       = a0v[r];
                gbufA[row][(nt0 + 1) * 16 + mA] = a1v[r];
            }
        }
        bar_lds();   // bar1: gbufA visible; zshq free for rewrite

        // ---- D: wave-autonomous social + LSTM + publish + out + next frags --
        {
            const int hid = lane;

            // social ge for owned agents (poll h_{t-1}: published one full
            // step ago -> slack = D-rest + bar + C; first-try hits expected)
            float geA[2][4];
            #pragma unroll
            for (int a = 0; a < 2; a++) {
                int m = a ? m1w : m0w;
                if (sCnt[t][m] > 0) {
                    int cnt = sCnt[t][m];
                    float cv = 0.f;
                    if (t == 0) {
                        for (int n = 0; n < cnt; n++)
                            cv += p.h_in[sMidx[0][m][n] * 64 + lane];
                    } else {
                        const unsigned long long* hb =
                            p.hist + (size_t)(t - 1) * (N_AG * 64);
                        const unsigned tagw = (unsigned)t;
                        for (int n = 0; n < cnt; n++) {
                            int r = sMidx[t][m][n];
                            unsigned long long wd;
                            do { wd = __hip_atomic_load(&hb[r * 64 + lane],
                                     __ATOMIC_RELAXED, __HIP_MEMORY_SCOPE_AGENT);
                            } while ((unsigned)(wd >> 32) != tagw);
                            cv += __uint_as_float((unsigned)wd);
                        }
                    }
                    cvs[m][lane] = cv;                        // wave-local
                    float acc = sBsoc[lane];
                    const float* wp = &u.w.WefP[lane * 65];
                    #pragma unroll 8
                    for (int k = 0; k < 64; k++) acc += cvs[m][k] * wp[k];
                    es[m][lane] = fmaxf(acc, 0.f);            // wave-local
                    float g0 = 0.f, g1 = 0.f, g2 = 0.f, g3 = 0.f;
                    #pragma unroll 4
                    for (int s = 0; s < 64; s++) {
                        float ev = es[m][s];                  // broadcast
                        float4 w4 = u.w.Wce4[s * 64 + lane];
                        g0 += ev * w4.x; g1 += ev * w4.y;
                        g2 += ev * w4.z; g3 += ev * w4.w;
                    }
                    geA[a][0] = g0; geA[a][1] = g1; geA[a][2] = g2; geA[a][3] = g3;
                } else {
                    geA[a][0] = sEW0[hid];
                    geA[a][1] = sEW0[64 + hid];
                    geA[a][2] = sEW0[128 + hid];
                    geA[a][3] = sEW0[192 + hid];
                }
            }

            // LSTM (matvec output lanes == gate lanes; no shuffling)
            float hn0, hn1;
            {
                float gi = gbufA[m0w][hid]       + sBc[hid]       + geA[0][0];
                float gf = gbufA[m0w][64 + hid]  + sBc[64 + hid]  + geA[0][1];
                float gR = gbufA[m0w][128 + hid] + sBc[128 + hid] + geA[0][2];
                float go = gbufA[m0w][192 + hid] + sBc[192 + hid] + geA[0][3];
                float cn = fsigm(gf) * c0 + fsigm(gi) * ftanh(gR);
                hn0 = fsigm(go) * ftanh(cn);
                c0 = cn;
            }
            {
                float gi = gbufA[m1w][hid]       + sBc[hid]       + geA[1][0];
                float gf = gbufA[m1w][64 + hid]  + sBc[64 + hid]  + geA[1][1];
                float gR = gbufA[m1w][128 + hid] + sBc[128 + hid] + geA[1][2];
                float go = gbufA[m1w][192 + hid] + sBc[192 + hid] + geA[1][3];
                float cn = fsigm(gf) * c1 + fsigm(gi) * ftanh(gR);
                hn1 = fsigm(go) * ftanh(cn);
                c1 = cn;
            }

            // publish EARLY (max propagation slack before next step's poll)
            if (t <= 18) {
                unsigned long long* hp = p.hist + (size_t)t * (N_AG * 64);
                unsigned long long tg = ((unsigned long long)(t + 1)) << 32;
                if (sNeed[t][m0w])
                    __hip_atomic_store(&hp[(wbase + m0w) * 64 + hid],
                                       tg | (unsigned long long)__float_as_uint(hn0),
                                       __ATOMIC_RELAXED, __HIP_MEMORY_SCOPE_AGENT);
                if (sNeed[t][m1w])
                    __hip_atomic_store(&hp[(wbase + m1w) * 64 + hid],
                                       tg | (unsigned long long)__float_as_uint(hn1),
                                       __ATOMIC_RELAXED, __HIP_MEMORY_SCOPE_AGENT);
            }
            hs[m0w][hid] = hn0;          // wave-local
            hs[m1w][hid] = hn1;

            // out: butterfly (all lanes end with all 4 sums)
            float w0 = sWout[hid], w1 = sWout[64 + hid];
            float p00 = hn0 * w0, p01 = hn0 * w1;
            float p10 = hn1 * w0, p11 = hn1 * w1;
            #pragma unroll
            for (int off = 32; off >= 1; off >>= 1) {
                p00 += __shfl_xor(p00, off);
                p01 += __shfl_xor(p01, off);
                p10 += __shfl_xor(p10, off);
                p11 += __shfl_xor(p11, off);
            }
            float mk0 = sMask[t][m0w], mk1 = sMask[t][m1w];
            float o00 = (p00 + sBout[0]) * mk0, o01 = (p01 + sBout[1]) * mk0;
            float o10 = (p10 + sBout[0]) * mk1, o11 = (p11 + sBout[1]) * mk1;
            if (lane == 0)
                *(float2*)&p.out[(t * N_AG + wbase + m0w) * 2] = make_float2(o00, o01);
            if (lane == 1)
                *(float2*)&p.out[(t * N_AG + wbase + m1w) * 2] = make_float2(o10, o11);

            // next-step frags (r uses out[t-1] = op* saved from previous iter)
            if (t < STEPS - 1) {
                const int tn = t + 1;
                if (lane < 32) {
                    int a = lane & 1, s5r = lane >> 1;
                    int m = a ? m1w : m0w;
                    float px, py;
                    if (tn <= 10) { px = sX[tn][m][0]; py = sX[tn][m][1]; }
                    else          { px = a ? op1x : op0x;
                                    py = a ? op1y : op0y; }
                    float v[8];
                    #pragma unroll
                    for (int j = 0; j < 8; j++) {
                        float2 w2 = sWinP[s5r * 17 + j];
                        v[j] = fmaxf(w2.x * px + w2.y * py + sBinP[s5r * 9 + j], 0.f);
                    }
                    pack8(v, zshq[s5r * 17 + m], zslq[s5r * 17 + m]);
                } else if (lane < 48) {
                    int idx = lane - 32, a = idx & 1, s58 = idx >> 1;
                    int m = a ? m1w : m0w;
                    float v[8];
                    #pragma unroll
                    for (int j = 0; j < 8; j++) v[j] = hs[m][s58 * 8 + j];
                    pack8(v, zshq[(16 + s58) * 17 + m], zslq[(16 + s58) * 17 + m]);
                }
            }
            op0x = o00; op0y = o01;      // becomes out[t-1] for next iteration
            op1x = o10; op1y = o11;
        }
        bar_lds();   // bar2: next-step frags visible; gbufA free
    }
}

// ---------------------------------------------------------------------------
extern "C" void kernel_launch(void* const* d_in, const int* in_sizes, int n_in,
                              void* d_out, int out_size, void* d_ws, size_t ws_size,
                              hipStream_t stream)
{
    KP kp;
    kp.X     = (const float*)d_in[0];
    kp.masks = (const float*)d_in[1];
    kp.h_in  = (const float*)d_in[2];
    kp.c_in  = (const float*)d_in[3];
    // d_in[4] = Y (unused), d_in[5] = T_obs (=9), d_in[6] = T_pred (=19)
    kp.Win   = (const float*)d_in[7];
    kp.bin   = (const float*)d_in[8];
    kp.Wsoc  = (const float*)d_in[9];
    kp.bsoc  = (const float*)d_in[10];
    kp.Wih   = (const float*)d_in[11];
    kp.Whh   = (const float*)d_in[12];
    kp.bih   = (const float*)d_in[13];
    kp.bhh   = (const float*)d_in[14];
    kp.Wout  = (const float*)d_in[15];
    kp.bout  = (const float*)d_in[16];
    kp.out   = (float*)d_out;

    unsigned long long* hist = (unsigned long long*)d_ws;   // 19*2048*64 (8B each)
    float* Wef  = (float*)(hist + 19 * N_AG * 64);          // 4096
    int*   need = (int*)(Wef + 4096);                       // 19*2048
    int*   mcnt = need + 19 * N_AG;                         // 20*2048
    int*   midx = mcnt + STEPS * N_AG;                      // 20*2048*CAP
    int*   flags = midx + STEPS * N_AG * CAP;               // 32

    kp.hist = hist; kp.Wef = Wef; kp.need = need; kp.mcnt = mcnt;
    kp.midx = midx; kp.flags = flags;

    k_all<<<NSRV + 128, 512, 0, stream>>>(kp);
}

// Round 13
// 196.243 us; speedup vs baseline: 1.0801x; 1.0801x over previous
//
#include <hip/hip_runtime.h>
#include <math.h>

// ---------------------------------------------------------------------------
// SocialLstm: T=24, N=2048, INPUT_DIM=2, HIDDEN=64, MEDIATE=128, SOCIAL=64,
// OUT_DIM=2, N_SIZE=2, CELL=0.3, T_obs=9, T_pred=19, WIN=9.
//
// R13 = R11 (best measured: k_all 109us / 190 total) + three latency trims:
//  1. per-step table pipelining: prologue waits flags {0,1,20} only; phase D
//     of step t prefetches sCnt/sMidx/sNeed[t+1] (flags long set in steady
//     state) -> service work overlaps the first steps.
//  2. pairwise partner polls in A'' (cnt>=2: one spin covers two partners;
//     accumulation order unchanged -> bit-identical).
//  3. in-block partner short-circuit: read hs[r-wbase] from LDS (ordered by
//     bar4) instead of the global hist round trip.
// R12's wave-autonomous e-path REVERTED (regressed 109->132.6: serial matvec
// on the matched wave's barrier path + 147KB LDS).
// MFMA hi/lo bf16 split (ZhWh+ZlWh+ZhWl) verified R3-R12, absmax ~2e-3.
// ---------------------------------------------------------------------------

#define N_AG   2048
#define STEPS  20
#define CAP    12
#define NSRV   21
#define MAGIC  0x13572468

typedef short short8 __attribute__((ext_vector_type(8)));
typedef float f32x4  __attribute__((ext_vector_type(4)));
union FU { uint4 q; short8 v; };

__device__ __forceinline__ unsigned short bf16rne(float x) {
    unsigned u = __float_as_uint(x);
    unsigned r = (u + 0x7fff + ((u >> 16) & 1)) >> 16;
    return (unsigned short)r;
}

__device__ __forceinline__ int khash(int k) {
    return (int)(((unsigned)k * 2654435761u) >> 21);   // 11-bit bucket
}

__device__ __forceinline__ float fsigm(float x) {
    return __builtin_amdgcn_rcpf(1.f + __expf(-x));
}
__device__ __forceinline__ float ftanh(float x) {
    float e = __expf(2.f * x);
    return 1.f - 2.f * __builtin_amdgcn_rcpf(e + 1.f);
}

// LDS-only barrier (no vmcnt drain; global exchanges use the tag protocol).
__device__ __forceinline__ void bar_lds() {
    asm volatile("s_waitcnt lgkmcnt(0)\n\ts_barrier" ::: "memory");
}

__device__ __forceinline__ void ast(int* p_, int v) {
    __hip_atomic_store(p_, v, __ATOMIC_RELAXED, __HIP_MEMORY_SCOPE_AGENT);
}
__device__ __forceinline__ void astf(float* p_, float v) {
    __hip_atomic_store(p_, v, __ATOMIC_RELAXED, __HIP_MEMORY_SCOPE_AGENT);
}
__device__ __forceinline__ int ald(const int* p_) {
    return __hip_atomic_load(p_, __ATOMIC_RELAXED, __HIP_MEMORY_SCOPE_AGENT);
}
__device__ __forceinline__ void spinflag(const int* f_) {
    while (ald(f_) != MAGIC) { }
}

struct KP {
    const float *X, *masks, *h_in, *c_in;
    const float *Win, *bin, *Wsoc, *bsoc, *Wih, *Whh, *bih, *bhh, *Wout, *bout;
    float *Wef;
    int *mcnt, *midx, *need, *flags;
    float *out;
    unsigned long long *hist;    // 19 slices x [2048][64] of (tag<<32|f32bits)
};

__global__ __launch_bounds__(512, 1) void k_all(KP p)
{
    // ---- persist LDS ----
    __shared__ __align__(16) uint4 zshq[544];     // frag slot s5*17 + m
    __shared__ __align__(16) uint4 zslq[544];
    __shared__ float gbuf[16][258];
    __shared__ float cvs[16][64];
    __shared__ float hs[16][68];
    __shared__ float sWefP[64 * 65];
    __shared__ float2 sWinP[16 * 17];
    __shared__ float sBinP[16 * 9];
    __shared__ float sX[11][16][2];
    __shared__ float sMask[STEPS][16];
    __shared__ int   sCnt[STEPS][16];
    __shared__ int   sNeed[19][16];
    __shared__ int   sMidx[STEPS][16][CAP];
    __shared__ float sBsoc[64], sBc[256], sWout[128], sBout[2];
    __shared__ uint4 sE0h[8], sE0l[8];
    __shared__ float olocal[2][16][2];
    // ---- service LDS ----
    __shared__ int kk[N_AG];
    __shared__ int head[N_AG];
    __shared__ int nxt[N_AG];
    __shared__ float red[512];

    const int tid = threadIdx.x;
    const int bxg = blockIdx.x;

    // =====================================================================
    // SERVICE BLOCKS 0..20  (unchanged from R11)
    // =====================================================================
    if (bxg < NSRV) {
        const int sb = bxg;
        {   // out-tail zero slice (frames 20..23 = 16384 floats)
            int lo = sb * 780;
            int hi = (sb == NSRV - 1) ? 16384 : lo + 780;
            for (int i = lo + tid; i < hi; i += 512)
                p.out[20 * N_AG * 2 + i] = 0.f;
        }
        if (sb == 20) {           // We fold
            for (int i = tid; i < 4096; i += 512) {
                int s = i >> 6, k = i & 63;
                float a = 0.f;
                #pragma unroll
                for (int w = 0; w < 9; w++) a += p.Wsoc[s * 576 + w * 64 + k];
                astf(&p.Wef[i], a);
            }
            __syncthreads();
            if (tid == 0) ast(&p.flags[20], MAGIC);
            return;
        }

        const int t = sb;
        const float* Xt = p.X + t * N_AG * 2;

        float mnx = 1e30f, mny = 1e30f;
        for (int i = tid; i < N_AG; i += 512) {
            mnx = fminf(mnx, Xt[2 * i]);
            mny = fminf(mny, Xt[2 * i + 1]);
        }
        red[tid] = mnx; __syncthreads();
        for (int s = 256; s > 0; s >>= 1) { if (tid < s) red[tid] = fminf(red[tid], red[tid + s]); __syncthreads(); }
        float ltx = red[0]; __syncthreads();
        red[tid] = mny; __syncthreads();
        for (int s = 256; s > 0; s >>= 1) { if (tid < s) red[tid] = fminf(red[tid], red[tid + s]); __syncthreads(); }
        float lty = red[0]; __syncthreads();
        ltx -= 1.2f;   // margin = 2*N_SIZE*CELL
        lty -= 1.2f;

        for (int i = tid; i < N_AG; i += 512) {
            float m = p.masks[t * N_AG + i];
            int px = (int)floorf((Xt[2 * i]     - ltx) / 0.3f);
            int py = (int)floorf((Xt[2 * i + 1] - lty) / 0.3f);
            int im = (int)m;
            px *= im; py *= im;
            kk[i] = px * 65536 + py;    // masked -> 0; real agents px,py >= 4
            head[i] = -1;
            if (t >= 1) ast(&p.need[(t - 1) * N_AG + i], 0);
        }
        __syncthreads();
        for (int j = tid; j < N_AG; j += 512) {
            int kj = kk[j];
            if (kj != 0) nxt[j] = atomicExch(&head[khash(kj)], j);
        }
        __syncthreads();
        for (int i = tid; i < N_AG; i += 512) {
            int ki = kk[i];
            int cnt = 0;
            int base = (t * N_AG + i) * CAP;
            if (ki != 0) {
                int tkey = ki - 65537;
                int lst[CAP];
                for (int j = head[khash(tkey)]; j >= 0; j = nxt[j]) {
                    if (kk[j] == tkey) { if (cnt < CAP) lst[cnt] = j; cnt++; }
                }
                if (cnt > CAP) cnt = CAP;
                for (int a = 1; a < cnt; a++) {       // ascending j = ref order
                    int v = lst[a]; int b = a - 1;
                    while (b >= 0 && lst[b] > v) { lst[b + 1] = lst[b]; b--; }
                    lst[b + 1] = v;
                }
                for (int a = 0; a < cnt; a++) {
                    ast(&p.midx[base + a], lst[a]);
                    if (t >= 1) ast(&p.need[(t - 1) * N_AG + lst[a]], 1);
                }
            }
            ast(&p.mcnt[t * N_AG + i], cnt);
        }
        __syncthreads();          // all waves' table stores acked
        if (tid == 0) ast(&p.flags[t], MAGIC);
        return;
    }

    // =====================================================================
    // PERSIST BLOCKS 21..148  (R11 structure + latency trims)
    // =====================================================================
    const int bx    = bxg - NSRV;
    const int wbase = bx * 16;
    const int wv    = tid >> 6, lane = tid & 63;
    const int mA    = lane & 15, quad = lane >> 4;
    const int nt0   = 2 * wv;

    // ---- prologue part A (independent of service tables) ----
    if (tid < 256) sBc[tid] = p.bih[tid] + p.bhh[tid];
    if (tid < 128) {
        sWout[tid] = p.Wout[tid];
        int c = tid;
        sWinP[(c >> 3) * 17 + (c & 7)] = make_float2(p.Win[2 * c], p.Win[2 * c + 1]);
        sBinP[(c >> 3) * 9 + (c & 7)] = p.bin[c];
    }
    if (tid < 64) sBsoc[tid] = p.bsoc[tid];
    if (tid < 2)  sBout[tid] = p.bout[tid];
    if (tid < 8) {
        unsigned uh[4], ul[4];
        #pragma unroll
        for (int w = 0; w < 4; w++) {
            float v0 = fmaxf(p.bsoc[tid * 8 + 2 * w], 0.f);
            float v1 = fmaxf(p.bsoc[tid * 8 + 2 * w + 1], 0.f);
            unsigned short h0 = bf16rne(v0), h1 = bf16rne(v1);
            float f0 = __uint_as_float(((unsigned)h0) << 16);
            float f1 = __uint_as_float(((unsigned)h1) << 16);
            unsigned short l0 = bf16rne(v0 - f0), l1 = bf16rne(v1 - f1);
            uh[w] = (unsigned)h0 | ((unsigned)h1 << 16);
            ul[w] = (unsigned)l0 | ((unsigned)l1 << 16);
        }
        sE0h[tid] = make_uint4(uh[0], uh[1], uh[2], uh[3]);
        sE0l[tid] = make_uint4(ul[0], ul[1], ul[2], ul[3]);
    }
    if (tid < 352) { int tt = tid / 32, r = tid % 32;
                     sX[tt][r >> 1][r & 1] = p.X[tt * (N_AG * 2) + (wbase + (r >> 1)) * 2 + (r & 1)]; }
    if (tid < 320) { int tt = tid / 16, m2 = tid % 16;
                     sMask[tt][m2] = p.masks[tt * N_AG + wbase + m2]; }

    // own h (LDS) + c (registers)
    float c0, c1;
    {
        int m0 = tid >> 6, h0i = tid & 63, m1 = m0 + 8;
        hs[m0][h0i] = p.h_in[(wbase + m0) * 64 + h0i];
        hs[m1][h0i] = p.h_in[(wbase + m1) * 64 + h0i];
        c0 = p.c_in[(wbase + m0) * 64 + h0i];
        c1 = p.c_in[(wbase + m1) * 64 + h0i];
    }

    // register-resident W fragments (hi/lo split), loaded once
    FU wh[2][8], wl[2][8];
    #pragma unroll
    for (int e = 0; e < 2; e++) {
        int g = (nt0 + e) * 16 + mA;
        #pragma unroll
        for (int kt = 0; kt < 8; kt++) {
            int k0 = kt * 32 + quad * 8;        // 8-run never crosses 192 boundary
            const float* src = (k0 < 192) ? (p.Wih + g * 192 + k0)
                                          : (p.Whh + g * 64 + (k0 - 192));
            unsigned uh[4], ul[4];
            #pragma unroll
            for (int w = 0; w < 4; w++) {
                float a = src[2 * w], b = src[2 * w + 1];
                unsigned short ha = bf16rne(a), hb = bf16rne(b);
                float fa = __uint_as_float(((unsigned)ha) << 16);
                float fb = __uint_as_float(((unsigned)hb) << 16);
                unsigned short la = bf16rne(a - fa), lb = bf16rne(b - fb);
                uh[w] = (unsigned)ha | ((unsigned)hb << 16);
                ul[w] = (unsigned)la | ((unsigned)lb << 16);
            }
            wh[e][kt].q = make_uint4(uh[0], uh[1], uh[2], uh[3]);
            wl[e][kt].q = make_uint4(ul[0], ul[1], ul[2], ul[3]);
        }
    }

    // ---- prologue part B: t=0 tables + Wef only (targeted flag spins) ----
    if (tid < 16) { spinflag(&p.flags[0]);
                    sCnt[0][tid] = ald(&p.mcnt[0 * N_AG + wbase + tid]); }
    else if (tid < 32) { spinflag(&p.flags[1]);
                    sNeed[0][tid - 16] = ald(&p.need[0 * N_AG + wbase + (tid - 16)]); }
    else if (tid >= 64 && tid < 64 + 192) {
        spinflag(&p.flags[0]);
        int q = tid - 64; int m2 = q / CAP, n = q % CAP;
        sMidx[0][m2][n] = ald(&p.midx[(0 * N_AG + wbase + m2) * CAP + n]);
    }
    {
        spinflag(&p.flags[20]);
        for (int i = tid; i < 4096; i += 512)
            sWefP[(i >> 6) * 65 + (i & 63)] = p.Wef[i];
    }
    __syncthreads();

    // =================== recurrence (R11 structure) ===================
    #pragma unroll 1
    for (int t = 0; t < STEPS; t++) {
        const int m5 = tid >> 5, s5 = tid & 31;
        const int cnt5 = sCnt[t][m5];

        // ---- B1: r-frags, h-frags, const-e-frags for unmatched ----
        {
            if (s5 < 16) {                       // r-cols c = s5*8 + j
                float px, py;
                if (t <= 10) { px = sX[t][m5][0];         py = sX[t][m5][1]; }
                else         { px = olocal[t & 1][m5][0]; py = olocal[t & 1][m5][1]; }
                float v[8];
                #pragma unroll
                for (int j = 0; j < 8; j++) {
                    float2 w2 = sWinP[s5 * 17 + j];
                    v[j] = fmaxf(w2.x * px + w2.y * py + sBinP[s5 * 9 + j], 0.f);
                }
                unsigned uh[4], ul[4];
                #pragma unroll
                for (int w = 0; w < 4; w++) {
                    float v0 = v[2 * w], v1 = v[2 * w + 1];
                    unsigned short h0 = bf16rne(v0), h1 = bf16rne(v1);
                    float f0 = __uint_as_float(((unsigned)h0) << 16);
                    float f1 = __uint_as_float(((unsigned)h1) << 16);
                    unsigned short l0 = bf16rne(v0 - f0), l1 = bf16rne(v1 - f1);
                    uh[w] = (unsigned)h0 | ((unsigned)h1 << 16);
                    ul[w] = (unsigned)l0 | ((unsigned)l1 << 16);
                }
                zshq[s5 * 17 + m5] = make_uint4(uh[0], uh[1], uh[2], uh[3]);
                zslq[s5 * 17 + m5] = make_uint4(ul[0], ul[1], ul[2], ul[3]);
            } else if (s5 < 24) {                // e-cols: const frag if unmatched
                if (cnt5 == 0) {
                    zshq[s5 * 17 + m5] = sE0h[s5 - 16];
                    zslq[s5 * 17 + m5] = sE0l[s5 - 16];
                }
            } else {                             // h-cols
                float v[8];
                #pragma unroll
                for (int j = 0; j < 8; j++) v[j] = hs[m5][(s5 - 24) * 8 + j];
                unsigned uh[4], ul[4];
                #pragma unroll
                for (int w = 0; w < 4; w++) {
                    float v0 = v[2 * w], v1 = v[2 * w + 1];
                    unsigned short h0 = bf16rne(v0), h1 = bf16rne(v1);
                    float f0 = __uint_as_float(((unsigned)h0) << 16);
                    float f1 = __uint_as_float(((unsigned)h1) << 16);
                    unsigned short l0 = bf16rne(v0 - f0), l1 = bf16rne(v1 - f1);
                    uh[w] = (unsigned)h0 | ((unsigned)h1 << 16);
                    ul[w] = (unsigned)l0 | ((unsigned)l1 << 16);
                }
                zshq[s5 * 17 + m5] = make_uint4(uh[0], uh[1], uh[2], uh[3]);
                zslq[s5 * 17 + m5] = make_uint4(ul[0], ul[1], ul[2], ul[3]);
            }
        }
        bar_lds();   // bar1: r/h/const-e frags visible

        // ---- A'': matched half-waves gather + e-dot + shuffle-frag ----
        if (cnt5 > 0) {
            float a0 = 0.f, a1 = 0.f;
            if (t == 0) {
                for (int n = 0; n < cnt5; n++) {
                    int r = sMidx[0][m5][n];
                    a0 += p.h_in[r * 64 + s5];
                    a1 += p.h_in[r * 64 + s5 + 32];
                }
            } else {
                const unsigned long long* hb = p.hist + (size_t)(t - 1) * (N_AG * 64);
                const unsigned tagw = (unsigned)t;
                int n = 0;
                // pairwise batched polls (one spin covers two partners)
                while (n + 1 < cnt5) {
                    int r0 = sMidx[t][m5][n], r1 = sMidx[t][m5][n + 1];
                    bool in0 = (unsigned)(r0 - wbase) < 16u;
                    bool in1 = (unsigned)(r1 - wbase) < 16u;
                    float b00, b01, b10, b11;
                    if (in0) { b00 = hs[r0 - wbase][s5]; b01 = hs[r0 - wbase][s5 + 32]; }
                    if (in1) { b10 = hs[r1 - wbase][s5]; b11 = hs[r1 - wbase][s5 + 32]; }
                    if (!in0 || !in1) {
                        unsigned long long w00, w01, w10, w11;
                        bool bad;
                        do {
                            bad = false;
                            if (!in0) {
                                w00 = __hip_atomic_load(&hb[r0 * 64 + s5], __ATOMIC_RELAXED, __HIP_MEMORY_SCOPE_AGENT);
                                w01 = __hip_atomic_load(&hb[r0 * 64 + s5 + 32], __ATOMIC_RELAXED, __HIP_MEMORY_SCOPE_AGENT);
                                bad |= ((unsigned)(w00 >> 32) != tagw) | ((unsigned)(w01 >> 32) != tagw);
                            }
                            if (!in1) {
                                w10 = __hip_atomic_load(&hb[r1 * 64 + s5], __ATOMIC_RELAXED, __HIP_MEMORY_SCOPE_AGENT);
                                w11 = __hip_atomic_load(&hb[r1 * 64 + s5 + 32], __ATOMIC_RELAXED, __HIP_MEMORY_SCOPE_AGENT);
                                bad |= ((unsigned)(w10 >> 32) != tagw) | ((unsigned)(w11 >> 32) != tagw);
                            }
                        } while (bad);
                        if (!in0) { b00 = __uint_as_float((unsigned)w00); b01 = __uint_as_float((unsigned)w01); }
                        if (!in1) { b10 = __uint_as_float((unsigned)w10); b11 = __uint_as_float((unsigned)w11); }
                    }
                    a0 += b00; a1 += b01;     // ascending-j order preserved
                    a0 += b10; a1 += b11;
                    n += 2;
                }
                if (n < cnt5) {
                    int r = sMidx[t][m5][n];
                    if ((unsigned)(r - wbase) < 16u) {
                        a0 += hs[r - wbase][s5];
                        a1 += hs[r - wbase][s5 + 32];
                    } else {
                        unsigned long long w0, w1;
                        do {
                            w0 = __hip_atomic_load(&hb[r * 64 + s5], __ATOMIC_RELAXED, __HIP_MEMORY_SCOPE_AGENT);
                            w1 = __hip_atomic_load(&hb[r * 64 + s5 + 32], __ATOMIC_RELAXED, __HIP_MEMORY_SCOPE_AGENT);
                        } while ((unsigned)(w0 >> 32) != tagw || (unsigned)(w1 >> 32) != tagw);
                        a0 += __uint_as_float((unsigned)w0);
                        a1 += __uint_as_float((unsigned)w1);
                    }
                }
            }
            cvs[m5][s5] = a0; cvs[m5][s5 + 32] = a1;
            float acc0 = sBsoc[s5], acc1 = sBsoc[s5 + 32];
            const float* w0p = &sWefP[s5 * 65];
            const float* w1p = &sWefP[(s5 + 32) * 65];
            for (int k = 0; k < 64; k++) {
                float cv = cvs[m5][k];
                acc0 += cv * w0p[k];
                acc1 += cv * w1p[k];
            }
            acc0 = fmaxf(acc0, 0.f);
            acc1 = fmaxf(acc1, 0.f);
            const int base = (m5 & 1) * 32;
            float v[8];
            #pragma unroll
            for (int jj = 0; jj < 8; jj++) {
                int c = s5 * 8 + jj;             // meaningful for s5<8
                int srcl = base + ((c < 32 ? c : c - 32) & 31);
                float va = __shfl(acc0, srcl, 64);
                float vb = __shfl(acc1, srcl, 64);
                v[jj] = (c < 32) ? va : vb;
            }
            if (s5 < 8) {
                unsigned uh[4], ul[4];
                #pragma unroll
                for (int w = 0; w < 4; w++) {
                    float v0 = v[2 * w], v1 = v[2 * w + 1];
                    unsigned short h0 = bf16rne(v0), h1 = bf16rne(v1);
                    float f0 = __uint_as_float(((unsigned)h0) << 16);
                    float f1 = __uint_as_float(((unsigned)h1) << 16);
                    unsigned short l0 = bf16rne(v0 - f0), l1 = bf16rne(v1 - f1);
                    uh[w] = (unsigned)h0 | ((unsigned)h1 << 16);
                    ul[w] = (unsigned)l0 | ((unsigned)l1 << 16);
                }
                zshq[(16 + s5) * 17 + m5] = make_uint4(uh[0], uh[1], uh[2], uh[3]);
                zslq[(16 + s5) * 17 + m5] = make_uint4(ul[0], ul[1], ul[2], ul[3]);
            }
        }

        // ---- C1: r/h k-tiles (0..3, 6, 7) — overlaps other waves' polls ----
        f32x4 a0v = {0.f, 0.f, 0.f, 0.f};
        f32x4 a1v = {0.f, 0.f, 0.f, 0.f};
        #pragma unroll
        for (int u = 0; u < 6; u++) {
            const int kt = (u < 4) ? u : u + 2;   // 0,1,2,3,6,7
            int fi = (kt * 4 + quad) * 17 + mA;
            FU az, bz;
            az.q = zshq[fi];
            bz.q = zslq[fi];
            a0v = __builtin_amdgcn_mfma_f32_16x16x32_bf16(az.v, wh[0][kt].v, a0v, 0, 0, 0);
            a1v = __builtin_amdgcn_mfma_f32_16x16x32_bf16(az.v, wh[1][kt].v, a1v, 0, 0, 0);
            a0v = __builtin_amdgcn_mfma_f32_16x16x32_bf16(bz.v, wh[0][kt].v, a0v, 0, 0, 0);
            a1v = __builtin_amdgcn_mfma_f32_16x16x32_bf16(bz.v, wh[1][kt].v, a1v, 0, 0, 0);
            a0v = __builtin_amdgcn_mfma_f32_16x16x32_bf16(az.v, wl[0][kt].v, a0v, 0, 0, 0);
            a1v = __builtin_amdgcn_mfma_f32_16x16x32_bf16(az.v, wl[1][kt].v, a1v, 0, 0, 0);
        }
        bar_lds();   // bar2: e-frags visible, all C1 issued

        // ---- C2: e k-tiles (4, 5); write gbuf ----
        #pragma unroll
        for (int kt = 4; kt <= 5; kt++) {
            int fi = (kt * 4 + quad) * 17 + mA;
            FU az, bz;
            az.q = zshq[fi];
            bz.q = zslq[fi];
            a0v = __builtin_amdgcn_mfma_f32_16x16x32_bf16(az.v, wh[0][kt].v, a0v, 0, 0, 0);
            a1v = __builtin_amdgcn_mfma_f32_16x16x32_bf16(az.v, wh[1][kt].v, a1v, 0, 0, 0);
            a0v = __builtin_amdgcn_mfma_f32_16x16x32_bf16(bz.v, wh[0][kt].v, a0v, 0, 0, 0);
            a1v = __builtin_amdgcn_mfma_f32_16x16x32_bf16(bz.v, wh[1][kt].v, a1v, 0, 0, 0);
            a0v = __builtin_amdgcn_mfma_f32_16x16x32_bf16(az.v, wl[0][kt].v, a0v, 0, 0, 0);
            a1v = __builtin_amdgcn_mfma_f32_16x16x32_bf16(az.v, wl[1][kt].v, a1v, 0, 0, 0);
        }
        #pragma unroll
        for (int r = 0; r < 4; r++) {
            int row = quad * 4 + r;           // agent slot
            gbuf[row][nt0 * 16 + mA]       = a0v[r];
            gbuf[row][(nt0 + 1) * 16 + mA] = a1v[r];
        }
        bar_lds();   // bar3: gbuf visible

        // ---- D: LSTM; tagged publish; out reduce; t+1 table prefetch ----
        {
            int m0 = tid >> 6, hid = tid & 63, m1 = m0 + 8;
            float hn0, hn1;
            {
                float gi = gbuf[m0][hid]       + sBc[hid];
                float gf = gbuf[m0][64 + hid]  + sBc[64 + hid];
                float gR = gbuf[m0][128 + hid] + sBc[128 + hid];
                float go = gbuf[m0][192 + hid] + sBc[192 + hid];
                float cn = fsigm(gf) * c0 + fsigm(gi) * ftanh(gR);
                hn0 = fsigm(go) * ftanh(cn);
                c0 = cn;
                hs[m0][hid] = hn0;
            }
            {
                float gi = gbuf[m1][hid]       + sBc[hid];
                float gf = gbuf[m1][64 + hid]  + sBc[64 + hid];
                float gR = gbuf[m1][128 + hid] + sBc[128 + hid];
                float go = gbuf[m1][192 + hid] + sBc[192 + hid];
                float cn = fsigm(gf) * c1 + fsigm(gi) * ftanh(gR);
                hn1 = fsigm(go) * ftanh(cn);
                c1 = cn;
                hs[m1][hid] = hn1;
            }
            if (t <= 18) {
                unsigned long long* hp = p.hist + (size_t)t * (N_AG * 64);
                unsigned long long tg = ((unsigned long long)(t + 1)) << 32;
                if (sNeed[t][m0])
                    __hip_atomic_store(&hp[(wbase + m0) * 64 + hid],
                                       tg | (unsigned long long)__float_as_uint(hn0),
                                       __ATOMIC_RELAXED, __HIP_MEMORY_SCOPE_AGENT);
                if (sNeed[t][m1])
                    __hip_atomic_store(&hp[(wbase + m1) * 64 + hid],
                                       tg | (unsigned long long)__float_as_uint(hn1),
                                       __ATOMIC_RELAXED, __HIP_MEMORY_SCOPE_AGENT);
            }

            float w0 = sWout[hid], w1 = sWout[64 + hid];
            float p00 = hn0 * w0, p01 = hn0 * w1;
            float p10 = hn1 * w0, p11 = hn1 * w1;
            #pragma unroll
            for (int off = 32; off >= 1; off >>= 1) {
                p00 += __shfl_xor(p00, off);
                p01 += __shfl_xor(p01, off);
                p10 += __shfl_xor(p10, off);
                p11 += __shfl_xor(p11, off);
            }
            if (hid == 0) {
                float mk0 = sMask[t][m0], mk1 = sMask[t][m1];
                float o00 = (p00 + sBout[0]) * mk0, o01 = (p01 + sBout[1]) * mk0;
                float o10 = (p10 + sBout[0]) * mk1, o11 = (p11 + sBout[1]) * mk1;
                p.out[(t * N_AG + wbase + m0) * 2 + 0] = o00;
                p.out[(t * N_AG + wbase + m0) * 2 + 1] = o01;
                p.out[(t * N_AG + wbase + m1) * 2 + 0] = o10;
                p.out[(t * N_AG + wbase + m1) * 2 + 1] = o11;
                olocal[t & 1][m0][0] = o00; olocal[t & 1][m0][1] = o01;
                olocal[t & 1][m1][0] = o10; olocal[t & 1][m1][1] = o11;
            }

            // prefetch t+1 tables (flags set long ago in steady state)
            if (t < STEPS - 1) {
                const int tn = t + 1;
                if (tid < 16) {
                    spinflag(&p.flags[tn]);
                    sCnt[tn][tid] = ald(&p.mcnt[tn * N_AG + wbase + tid]);
                } else if (tid < 32 && tn <= 18) {
                    spinflag(&p.flags[tn + 1]);
                    sNeed[tn][tid - 16] = ald(&p.need[tn * N_AG + wbase + (tid - 16)]);
                } else if (tid >= 64 && tid < 64 + 192) {
                    spinflag(&p.flags[tn]);
                    int q = tid - 64; int m2 = q / CAP, n = q % CAP;
                    sMidx[tn][m2][n] = ald(&p.midx[(tn * N_AG + wbase + m2) * CAP + n]);
                }
            }
        }
        bar_lds();   // bar4: hs + olocal + t+1 tables stable before next step
    }
}

// ---------------------------------------------------------------------------
extern "C" void kernel_launch(void* const* d_in, const int* in_sizes, int n_in,
                              void* d_out, int out_size, void* d_ws, size_t ws_size,
                              hipStream_t stream)
{
    KP kp;
    kp.X     = (const float*)d_in[0];
    kp.masks = (const float*)d_in[1];
    kp.h_in  = (const float*)d_in[2];
    kp.c_in  = (const float*)d_in[3];
    // d_in[4] = Y (unused), d_in[5] = T_obs (=9), d_in[6] = T_pred (=19)
    kp.Win   = (const float*)d_in[7];
    kp.bin   = (const float*)d_in[8];
    kp.Wsoc  = (const float*)d_in[9];
    kp.bsoc  = (const float*)d_in[10];
    kp.Wih   = (const float*)d_in[11];
    kp.Whh   = (const float*)d_in[12];
    kp.bih   = (const float*)d_in[13];
    kp.bhh   = (const float*)d_in[14];
    kp.Wout  = (const float*)d_in[15];
    kp.bout  = (const float*)d_in[16];
    kp.out   = (float*)d_out;

    unsigned long long* hist = (unsigned long long*)d_ws;   // 19*2048*64 (8B each)
    float* Wef  = (float*)(hist + 19 * N_AG * 64);          // 4096
    int*   need = (int*)(Wef + 4096);                       // 19*2048
    int*   mcnt = need + 19 * N_AG;                         // 20*2048
    int*   midx = mcnt + STEPS * N_AG;                      // 20*2048*CAP
    int*   flags = midx + STEPS * N_AG * CAP;               // 32

    kp.hist = hist; kp.Wef = Wef; kp.need = need; kp.mcnt = mcnt;
    kp.midx = midx; kp.flags = flags;

    k_all<<<NSRV + 128, 512, 0, stream>>>(kp);
}

// Round 14
// 185.951 us; speedup vs baseline: 1.1399x; 1.0553x over previous
//
#include <hip/hip_runtime.h>
#include <math.h>

// ---------------------------------------------------------------------------
// SocialLstm: T=24, N=2048, INPUT_DIM=2, HIDDEN=64, MEDIATE=128, SOCIAL=64,
// OUT_DIM=2, N_SIZE=2, CELL=0.3, T_obs=9, T_pred=19, WIN=9.
//
// R14 = R11 (best measured: k_all 109.4us / 190.0 total) + ONE change:
//  A'' poll prefetch: the first partner's two tagged loads are issued
//  BEFORE C1 and validated AFTER it -> the ~900cyc coherent-point round
//  trip overlaps C1's 36 MFMAs instead of preceding them. Worst case
//  (stale tag) identical to R11. Accumulation order preserved ->
//  bit-identical output.
// R13's three trims REVERTED (all regressed: per-step table prefetch put
// spins on the barrier path; pairwise/in-block poll branches bloated A'').
// MFMA hi/lo bf16 split (ZhWh+ZlWh+ZhWl) verified R3-R13, absmax ~2e-3.
// ---------------------------------------------------------------------------

#define N_AG   2048
#define STEPS  20
#define CAP    12
#define NSRV   21
#define MAGIC  0x13572468

typedef short short8 __attribute__((ext_vector_type(8)));
typedef float f32x4  __attribute__((ext_vector_type(4)));
union FU { uint4 q; short8 v; };

__device__ __forceinline__ unsigned short bf16rne(float x) {
    unsigned u = __float_as_uint(x);
    unsigned r = (u + 0x7fff + ((u >> 16) & 1)) >> 16;
    return (unsigned short)r;
}

__device__ __forceinline__ int khash(int k) {
    return (int)(((unsigned)k * 2654435761u) >> 21);   // 11-bit bucket
}

__device__ __forceinline__ float fsigm(float x) {
    return __builtin_amdgcn_rcpf(1.f + __expf(-x));
}
__device__ __forceinline__ float ftanh(float x) {
    float e = __expf(2.f * x);
    return 1.f - 2.f * __builtin_amdgcn_rcpf(e + 1.f);
}

// LDS-only barrier (no vmcnt drain; global exchanges use the tag protocol).
__device__ __forceinline__ void bar_lds() {
    asm volatile("s_waitcnt lgkmcnt(0)\n\ts_barrier" ::: "memory");
}

__device__ __forceinline__ void ast(int* p_, int v) {
    __hip_atomic_store(p_, v, __ATOMIC_RELAXED, __HIP_MEMORY_SCOPE_AGENT);
}
__device__ __forceinline__ void astf(float* p_, float v) {
    __hip_atomic_store(p_, v, __ATOMIC_RELAXED, __HIP_MEMORY_SCOPE_AGENT);
}
__device__ __forceinline__ unsigned long long aldu64(const unsigned long long* p_) {
    return __hip_atomic_load(p_, __ATOMIC_RELAXED, __HIP_MEMORY_SCOPE_AGENT);
}

struct KP {
    const float *X, *masks, *h_in, *c_in;
    const float *Win, *bin, *Wsoc, *bsoc, *Wih, *Whh, *bih, *bhh, *Wout, *bout;
    float *Wef;
    int *mcnt, *midx, *need, *flags;
    float *out;
    unsigned long long *hist;    // 19 slices x [2048][64] of (tag<<32|f32bits)
};

__global__ __launch_bounds__(512, 1) void k_all(KP p)
{
    // ---- persist LDS ----
    __shared__ __align__(16) uint4 zshq[544];     // frag slot s5*17 + m
    __shared__ __align__(16) uint4 zslq[544];
    __shared__ float gbuf[16][258];
    __shared__ float cvs[16][64];
    __shared__ float hs[16][68];
    __shared__ float sWefP[64 * 65];
    __shared__ float2 sWinP[16 * 17];
    __shared__ float sBinP[16 * 9];
    __shared__ float sX[11][16][2];
    __shared__ float sMask[STEPS][16];
    __shared__ int   sCnt[STEPS][16];
    __shared__ int   sNeed[19][16];
    __shared__ int   sMidx[STEPS][16][CAP];
    __shared__ float sBsoc[64], sBc[256], sWout[128], sBout[2];
    __shared__ uint4 sE0h[8], sE0l[8];
    __shared__ float olocal[2][16][2];
    // ---- service LDS ----
    __shared__ int kk[N_AG];
    __shared__ int head[N_AG];
    __shared__ int nxt[N_AG];
    __shared__ float red[512];

    const int tid = threadIdx.x;
    const int bxg = blockIdx.x;

    // =====================================================================
    // SERVICE BLOCKS 0..20  (unchanged from R11)
    // =====================================================================
    if (bxg < NSRV) {
        const int sb = bxg;
        {   // out-tail zero slice (frames 20..23 = 16384 floats)
            int lo = sb * 780;
            int hi = (sb == NSRV - 1) ? 16384 : lo + 780;
            for (int i = lo + tid; i < hi; i += 512)
                p.out[20 * N_AG * 2 + i] = 0.f;
        }
        if (sb == 20) {           // We fold
            for (int i = tid; i < 4096; i += 512) {
                int s = i >> 6, k = i & 63;
                float a = 0.f;
                #pragma unroll
                for (int w = 0; w < 9; w++) a += p.Wsoc[s * 576 + w * 64 + k];
                astf(&p.Wef[i], a);
            }
            __syncthreads();
            if (tid == 0) ast(&p.flags[20], MAGIC);
            return;
        }

        const int t = sb;
        const float* Xt = p.X + t * N_AG * 2;

        float mnx = 1e30f, mny = 1e30f;
        for (int i = tid; i < N_AG; i += 512) {
            mnx = fminf(mnx, Xt[2 * i]);
            mny = fminf(mny, Xt[2 * i + 1]);
        }
        red[tid] = mnx; __syncthreads();
        for (int s = 256; s > 0; s >>= 1) { if (tid < s) red[tid] = fminf(red[tid], red[tid + s]); __syncthreads(); }
        float ltx = red[0]; __syncthreads();
        red[tid] = mny; __syncthreads();
        for (int s = 256; s > 0; s >>= 1) { if (tid < s) red[tid] = fminf(red[tid], red[tid + s]); __syncthreads(); }
        float lty = red[0]; __syncthreads();
        ltx -= 1.2f;   // margin = 2*N_SIZE*CELL
        lty -= 1.2f;

        for (int i = tid; i < N_AG; i += 512) {
            float m = p.masks[t * N_AG + i];
            int px = (int)floorf((Xt[2 * i]     - ltx) / 0.3f);
            int py = (int)floorf((Xt[2 * i + 1] - lty) / 0.3f);
            int im = (int)m;
            px *= im; py *= im;
            kk[i] = px * 65536 + py;    // masked -> 0; real agents px,py >= 4
            head[i] = -1;
            if (t >= 1) ast(&p.need[(t - 1) * N_AG + i], 0);
        }
        __syncthreads();
        for (int j = tid; j < N_AG; j += 512) {
            int kj = kk[j];
            if (kj != 0) nxt[j] = atomicExch(&head[khash(kj)], j);
        }
        __syncthreads();
        for (int i = tid; i < N_AG; i += 512) {
            int ki = kk[i];
            int cnt = 0;
            int base = (t * N_AG + i) * CAP;
            if (ki != 0) {
                int tkey = ki - 65537;
                int lst[CAP];
                for (int j = head[khash(tkey)]; j >= 0; j = nxt[j]) {
                    if (kk[j] == tkey) { if (cnt < CAP) lst[cnt] = j; cnt++; }
                }
                if (cnt > CAP) cnt = CAP;
                for (int a = 1; a < cnt; a++) {       // ascending j = ref order
                    int v = lst[a]; int b = a - 1;
                    while (b >= 0 && lst[b] > v) { lst[b + 1] = lst[b]; b--; }
                    lst[b + 1] = v;
                }
                for (int a = 0; a < cnt; a++) {
                    ast(&p.midx[base + a], lst[a]);
                    if (t >= 1) ast(&p.need[(t - 1) * N_AG + lst[a]], 1);
                }
            }
            ast(&p.mcnt[t * N_AG + i], cnt);
        }
        __syncthreads();          // all waves' table stores acked
        if (tid == 0) ast(&p.flags[t], MAGIC);
        return;
    }

    // =====================================================================
    // PERSIST BLOCKS 21..148  (R11 structure)
    // =====================================================================
    const int bx    = bxg - NSRV;
    const int wbase = bx * 16;
    const int wv    = tid >> 6, lane = tid & 63;
    const int mA    = lane & 15, quad = lane >> 4;
    const int nt0   = 2 * wv;

    // ---- prologue part A (independent of service tables) ----
    if (tid < 256) sBc[tid] = p.bih[tid] + p.bhh[tid];
    if (tid < 128) {
        sWout[tid] = p.Wout[tid];
        int c = tid;
        sWinP[(c >> 3) * 17 + (c & 7)] = make_float2(p.Win[2 * c], p.Win[2 * c + 1]);
        sBinP[(c >> 3) * 9 + (c & 7)] = p.bin[c];
    }
    if (tid < 64) sBsoc[tid] = p.bsoc[tid];
    if (tid < 2)  sBout[tid] = p.bout[tid];
    if (tid < 8) {
        unsigned uh[4], ul[4];
        #pragma unroll
        for (int w = 0; w < 4; w++) {
            float v0 = fmaxf(p.bsoc[tid * 8 + 2 * w], 0.f);
            float v1 = fmaxf(p.bsoc[tid * 8 + 2 * w + 1], 0.f);
            unsigned short h0 = bf16rne(v0), h1 = bf16rne(v1);
            float f0 = __uint_as_float(((unsigned)h0) << 16);
            float f1 = __uint_as_float(((unsigned)h1) << 16);
            unsigned short l0 = bf16rne(v0 - f0), l1 = bf16rne(v1 - f1);
            uh[w] = (unsigned)h0 | ((unsigned)h1 << 16);
            ul[w] = (unsigned)l0 | ((unsigned)l1 << 16);
        }
        sE0h[tid] = make_uint4(uh[0], uh[1], uh[2], uh[3]);
        sE0l[tid] = make_uint4(ul[0], ul[1], ul[2], ul[3]);
    }
    if (tid < 352) { int tt = tid / 32, r = tid % 32;
                     sX[tt][r >> 1][r & 1] = p.X[tt * (N_AG * 2) + (wbase + (r >> 1)) * 2 + (r & 1)]; }
    if (tid < 320) { int tt = tid / 16, m2 = tid % 16;
                     sMask[tt][m2] = p.masks[tt * N_AG + wbase + m2]; }

    // own h (LDS) + c (registers)
    float c0, c1;
    {
        int m0 = tid >> 6, h0i = tid & 63, m1 = m0 + 8;
        hs[m0][h0i] = p.h_in[(wbase + m0) * 64 + h0i];
        hs[m1][h0i] = p.h_in[(wbase + m1) * 64 + h0i];
        c0 = p.c_in[(wbase + m0) * 64 + h0i];
        c1 = p.c_in[(wbase + m1) * 64 + h0i];
    }

    // register-resident W fragments (hi/lo split), loaded once
    FU wh[2][8], wl[2][8];
    #pragma unroll
    for (int e = 0; e < 2; e++) {
        int g = (nt0 + e) * 16 + mA;
        #pragma unroll
        for (int kt = 0; kt < 8; kt++) {
            int k0 = kt * 32 + quad * 8;        // 8-run never crosses 192 boundary
            const float* src = (k0 < 192) ? (p.Wih + g * 192 + k0)
                                          : (p.Whh + g * 64 + (k0 - 192));
            unsigned uh[4], ul[4];
            #pragma unroll
            for (int w = 0; w < 4; w++) {
                float a = src[2 * w], b = src[2 * w + 1];
                unsigned short ha = bf16rne(a), hb = bf16rne(b);
                float fa = __uint_as_float(((unsigned)ha) << 16);
                float fb = __uint_as_float(((unsigned)hb) << 16);
                unsigned short la = bf16rne(a - fa), lb = bf16rne(b - fb);
                uh[w] = (unsigned)ha | ((unsigned)hb << 16);
                ul[w] = (unsigned)la | ((unsigned)lb << 16);
            }
            wh[e][kt].q = make_uint4(uh[0], uh[1], uh[2], uh[3]);
            wl[e][kt].q = make_uint4(ul[0], ul[1], ul[2], ul[3]);
        }
    }

    // ---- wait for service flags (overlaps service work with prologue) ----
    if (tid < NSRV) {
        while (__hip_atomic_load(&p.flags[tid], __ATOMIC_RELAXED,
                                 __HIP_MEMORY_SCOPE_AGENT) != MAGIC) { }
    }
    __syncthreads();

    // ---- prologue part B: service tables (first-touch plain loads) ----
    if (tid < 320) { int tt = tid / 16, m2 = tid % 16;
                     sCnt[tt][m2] = p.mcnt[tt * N_AG + wbase + m2]; }
    if (tid < 304) { int s = tid / 16, m2 = tid % 16;
                     sNeed[s][m2] = p.need[s * N_AG + wbase + m2]; }
    for (int i = tid; i < 4096; i += 512) sWefP[(i >> 6) * 65 + (i & 63)] = p.Wef[i];
    for (int i = tid; i < STEPS * 16 * CAP; i += 512) {
        int tt = i / (16 * CAP), r = i % (16 * CAP), m2 = r / CAP, n = r % CAP;
        sMidx[tt][m2][n] = p.midx[(tt * N_AG + wbase + m2) * CAP + n];
    }
    __syncthreads();

    // =================== recurrence (R11 structure) ===================
    #pragma unroll 1
    for (int t = 0; t < STEPS; t++) {
        const int m5 = tid >> 5, s5 = tid & 31;
        const int cnt5 = sCnt[t][m5];

        // ---- B1: r-frags, h-frags, const-e-frags for unmatched ----
        {
            if (s5 < 16) {                       // r-cols c = s5*8 + j
                float px, py;
                if (t <= 10) { px = sX[t][m5][0];         py = sX[t][m5][1]; }
                else         { px = olocal[t & 1][m5][0]; py = olocal[t & 1][m5][1]; }
                float v[8];
                #pragma unroll
                for (int j = 0; j < 8; j++) {
                    float2 w2 = sWinP[s5 * 17 + j];
                    v[j] = fmaxf(w2.x * px + w2.y * py + sBinP[s5 * 9 + j], 0.f);
                }
                unsigned uh[4], ul[4];
                #pragma unroll
                for (int w = 0; w < 4; w++) {
                    float v0 = v[2 * w], v1 = v[2 * w + 1];
                    unsigned short h0 = bf16rne(v0), h1 = bf16rne(v1);
                    float f0 = __uint_as_float(((unsigned)h0) << 16);
                    float f1 = __uint_as_float(((unsigned)h1) << 16);
                    unsigned short l0 = bf16rne(v0 - f0), l1 = bf16rne(v1 - f1);
                    uh[w] = (unsigned)h0 | ((unsigned)h1 << 16);
                    ul[w] = (unsigned)l0 | ((unsigned)l1 << 16);
                }
                zshq[s5 * 17 + m5] = make_uint4(uh[0], uh[1], uh[2], uh[3]);
                zslq[s5 * 17 + m5] = make_uint4(ul[0], ul[1], ul[2], ul[3]);
            } else if (s5 < 24) {                // e-cols: const frag if unmatched
                if (cnt5 == 0) {
                    zshq[s5 * 17 + m5] = sE0h[s5 - 16];
                    zslq[s5 * 17 + m5] = sE0l[s5 - 16];
                }
            } else {                             // h-cols
                float v[8];
                #pragma unroll
                for (int j = 0; j < 8; j++) v[j] = hs[m5][(s5 - 24) * 8 + j];
                unsigned uh[4], ul[4];
                #pragma unroll
                for (int w = 0; w < 4; w++) {
                    float v0 = v[2 * w], v1 = v[2 * w + 1];
                    unsigned short h0 = bf16rne(v0), h1 = bf16rne(v1);
                    float f0 = __uint_as_float(((unsigned)h0) << 16);
                    float f1 = __uint_as_float(((unsigned)h1) << 16);
                    unsigned short l0 = bf16rne(v0 - f0), l1 = bf16rne(v1 - f1);
                    uh[w] = (unsigned)h0 | ((unsigned)h1 << 16);
                    ul[w] = (unsigned)l0 | ((unsigned)l1 << 16);
                }
                zshq[s5 * 17 + m5] = make_uint4(uh[0], uh[1], uh[2], uh[3]);
                zslq[s5 * 17 + m5] = make_uint4(ul[0], ul[1], ul[2], ul[3]);
            }
        }
        bar_lds();   // bar1: r/h/const-e frags visible

        // ---- A''-issue: first partner's tagged loads, no wait (t>0) ----
        const unsigned long long* hb = p.hist + (size_t)(t - 1) * (N_AG * 64);
        unsigned long long pw0 = 0, pw1 = 0;
        int rfirst = -1;
        if (cnt5 > 0 && t > 0) {
            rfirst = sMidx[t][m5][0];
            pw0 = aldu64(&hb[rfirst * 64 + s5]);        // in flight across C1
            pw1 = aldu64(&hb[rfirst * 64 + s5 + 32]);
        }

        // ---- C1: r/h k-tiles (0..3, 6, 7) — overlaps the poll round trip --
        f32x4 a0v = {0.f, 0.f, 0.f, 0.f};
        f32x4 a1v = {0.f, 0.f, 0.f, 0.f};
        #pragma unroll
        for (int u = 0; u < 6; u++) {
            const int kt = (u < 4) ? u : u + 2;   // 0,1,2,3,6,7
            int fi = (kt * 4 + quad) * 17 + mA;
            FU az, bz;
            az.q = zshq[fi];
            bz.q = zslq[fi];
            a0v = __builtin_amdgcn_mfma_f32_16x16x32_bf16(az.v, wh[0][kt].v, a0v, 0, 0, 0);
            a1v = __builtin_amdgcn_mfma_f32_16x16x32_bf16(az.v, wh[1][kt].v, a1v, 0, 0, 0);
            a0v = __builtin_amdgcn_mfma_f32_16x16x32_bf16(bz.v, wh[0][kt].v, a0v, 0, 0, 0);
            a1v = __builtin_amdgcn_mfma_f32_16x16x32_bf16(bz.v, wh[1][kt].v, a1v, 0, 0, 0);
            a0v = __builtin_amdgcn_mfma_f32_16x16x32_bf16(az.v, wl[0][kt].v, a0v, 0, 0, 0);
            a1v = __builtin_amdgcn_mfma_f32_16x16x32_bf16(az.v, wl[1][kt].v, a1v, 0, 0, 0);
        }

        // ---- A''-complete: validate/gather + e-dot + shuffle-frag ----
        if (cnt5 > 0) {
            float a0 = 0.f, a1 = 0.f;
            if (t == 0) {
                for (int n = 0; n < cnt5; n++) {
                    int r = sMidx[0][m5][n];
                    a0 += p.h_in[r * 64 + s5];
                    a1 += p.h_in[r * 64 + s5 + 32];
                }
            } else {
                const unsigned tagw = (unsigned)t;
                // partner 0: prefetched; retry only if stale
                while ((unsigned)(pw0 >> 32) != tagw || (unsigned)(pw1 >> 32) != tagw) {
                    pw0 = aldu64(&hb[rfirst * 64 + s5]);
                    pw1 = aldu64(&hb[rfirst * 64 + s5 + 32]);
                }
                a0 += __uint_as_float((unsigned)pw0);
                a1 += __uint_as_float((unsigned)pw1);
                for (int n = 1; n < cnt5; n++) {
                    int r = sMidx[t][m5][n];
                    unsigned long long w0, w1;
                    do {
                        w0 = aldu64(&hb[r * 64 + s5]);
                        w1 = aldu64(&hb[r * 64 + s5 + 32]);
                    } while ((unsigned)(w0 >> 32) != tagw || (unsigned)(w1 >> 32) != tagw);
                    a0 += __uint_as_float((unsigned)w0);
                    a1 += __uint_as_float((unsigned)w1);
                }
            }
            cvs[m5][s5] = a0; cvs[m5][s5 + 32] = a1;
            float acc0 = sBsoc[s5], acc1 = sBsoc[s5 + 32];
            const float* w0p = &sWefP[s5 * 65];
            const float* w1p = &sWefP[(s5 + 32) * 65];
            for (int k = 0; k < 64; k++) {
                float cv = cvs[m5][k];
                acc0 += cv * w0p[k];
                acc1 += cv * w1p[k];
            }
            acc0 = fmaxf(acc0, 0.f);
            acc1 = fmaxf(acc1, 0.f);
            const int base = (m5 & 1) * 32;
            float v[8];
            #pragma unroll
            for (int jj = 0; jj < 8; jj++) {
                int c = s5 * 8 + jj;             // meaningful for s5<8
                int srcl = base + ((c < 32 ? c : c - 32) & 31);
                float va = __shfl(acc0, srcl, 64);
                float vb = __shfl(acc1, srcl, 64);
                v[jj] = (c < 32) ? va : vb;
            }
            if (s5 < 8) {
                unsigned uh[4], ul[4];
                #pragma unroll
                for (int w = 0; w < 4; w++) {
                    float v0 = v[2 * w], v1 = v[2 * w + 1];
                    unsigned short h0 = bf16rne(v0), h1 = bf16rne(v1);
                    float f0 = __uint_as_float(((unsigned)h0) << 16);
                    float f1 = __uint_as_float(((unsigned)h1) << 16);
                    unsigned short l0 = bf16rne(v0 - f0), l1 = bf16rne(v1 - f1);
                    uh[w] = (unsigned)h0 | ((unsigned)h1 << 16);
                    ul[w] = (unsigned)l0 | ((unsigned)l1 << 16);
                }
                zshq[(16 + s5) * 17 + m5] = make_uint4(uh[0], uh[1], uh[2], uh[3]);
                zslq[(16 + s5) * 17 + m5] = make_uint4(ul[0], ul[1], ul[2], ul[3]);
            }
        }
        bar_lds();   // bar2: e-frags visible, all C1 issued

        // ---- C2: e k-tiles (4, 5); write gbuf ----
        #pragma unroll
        for (int kt = 4; kt <= 5; kt++) {
            int fi = (kt * 4 + quad) * 17 + mA;
            FU az, bz;
            az.q = zshq[fi];
            bz.q = zslq[fi];
            a0v = __builtin_amdgcn_mfma_f32_16x16x32_bf16(az.v, wh[0][kt].v, a0v, 0, 0, 0);
            a1v = __builtin_amdgcn_mfma_f32_16x16x32_bf16(az.v, wh[1][kt].v, a1v, 0, 0, 0);
            a0v = __builtin_amdgcn_mfma_f32_16x16x32_bf16(bz.v, wh[0][kt].v, a0v, 0, 0, 0);
            a1v = __builtin_amdgcn_mfma_f32_16x16x32_bf16(bz.v, wh[1][kt].v, a1v, 0, 0, 0);
            a0v = __builtin_amdgcn_mfma_f32_16x16x32_bf16(az.v, wl[0][kt].v, a0v, 0, 0, 0);
            a1v = __builtin_amdgcn_mfma_f32_16x16x32_bf16(az.v, wl[1][kt].v, a1v, 0, 0, 0);
        }
        #pragma unroll
        for (int r = 0; r < 4; r++) {
            int row = quad * 4 + r;           // agent slot
            gbuf[row][nt0 * 16 + mA]       = a0v[r];
            gbuf[row][(nt0 + 1) * 16 + mA] = a1v[r];
        }
        bar_lds();   // bar3: gbuf visible

        // ---- D: LSTM; tagged publish of needed h; E: out reduce ----
        {
            int m0 = tid >> 6, hid = tid & 63, m1 = m0 + 8;
            float hn0, hn1;
            {
                float gi = gbuf[m0][hid]       + sBc[hid];
                float gf = gbuf[m0][64 + hid]  + sBc[64 + hid];
                float gR = gbuf[m0][128 + hid] + sBc[128 + hid];
                float go = gbuf[m0][192 + hid] + sBc[192 + hid];
                float cn = fsigm(gf) * c0 + fsigm(gi) * ftanh(gR);
                hn0 = fsigm(go) * ftanh(cn);
                c0 = cn;
                hs[m0][hid] = hn0;
            }
            {
                float gi = gbuf[m1][hid]       + sBc[hid];
                float gf = gbuf[m1][64 + hid]  + sBc[64 + hid];
                float gR = gbuf[m1][128 + hid] + sBc[128 + hid];
                float go = gbuf[m1][192 + hid] + sBc[192 + hid];
                float cn = fsigm(gf) * c1 + fsigm(gi) * ftanh(gR);
                hn1 = fsigm(go) * ftanh(cn);
                c1 = cn;
                hs[m1][hid] = hn1;
            }
            if (t <= 18) {
                unsigned long long* hp = p.hist + (size_t)t * (N_AG * 64);
                unsigned long long tg = ((unsigned long long)(t + 1)) << 32;
                if (sNeed[t][m0])
                    __hip_atomic_store(&hp[(wbase + m0) * 64 + hid],
                                       tg | (unsigned long long)__float_as_uint(hn0),
                                       __ATOMIC_RELAXED, __HIP_MEMORY_SCOPE_AGENT);
                if (sNeed[t][m1])
                    __hip_atomic_store(&hp[(wbase + m1) * 64 + hid],
                                       tg | (unsigned long long)__float_as_uint(hn1),
                                       __ATOMIC_RELAXED, __HIP_MEMORY_SCOPE_AGENT);
            }

            float w0 = sWout[hid], w1 = sWout[64 + hid];
            float p00 = hn0 * w0, p01 = hn0 * w1;
            float p10 = hn1 * w0, p11 = hn1 * w1;
            #pragma unroll
            for (int off = 32; off >= 1; off >>= 1) {
                p00 += __shfl_xor(p00, off);
                p01 += __shfl_xor(p01, off);
                p10 += __shfl_xor(p10, off);
                p11 += __shfl_xor(p11, off);
            }
            if (hid == 0) {
                float mk0 = sMask[t][m0], mk1 = sMask[t][m1];
                float o00 = (p00 + sBout[0]) * mk0, o01 = (p01 + sBout[1]) * mk0;
                float o10 = (p10 + sBout[0]) * mk1, o11 = (p11 + sBout[1]) * mk1;
                p.out[(t * N_AG + wbase + m0) * 2 + 0] = o00;
                p.out[(t * N_AG + wbase + m0) * 2 + 1] = o01;
                p.out[(t * N_AG + wbase + m1) * 2 + 0] = o10;
                p.out[(t * N_AG + wbase + m1) * 2 + 1] = o11;
                olocal[t & 1][m0][0] = o00; olocal[t & 1][m0][1] = o01;
                olocal[t & 1][m1][0] = o10; olocal[t & 1][m1][1] = o11;
            }
        }
        bar_lds();   // bar4: hs + olocal stable before next step
    }
}

// ---------------------------------------------------------------------------
extern "C" void kernel_launch(void* const* d_in, const int* in_sizes, int n_in,
                              void* d_out, int out_size, void* d_ws, size_t ws_size,
                              hipStream_t stream)
{
    KP kp;
    kp.X     = (const float*)d_in[0];
    kp.masks = (const float*)d_in[1];
    kp.h_in  = (const float*)d_in[2];
    kp.c_in  = (const float*)d_in[3];
    // d_in[4] = Y (unused), d_in[5] = T_obs (=9), d_in[6] = T_pred (=19)
    kp.Win   = (const float*)d_in[7];
    kp.bin   = (const float*)d_in[8];
    kp.Wsoc  = (const float*)d_in[9];
    kp.bsoc  = (const float*)d_in[10];
    kp.Wih   = (const float*)d_in[11];
    kp.Whh   = (const float*)d_in[12];
    kp.bih   = (const float*)d_in[13];
    kp.bhh   = (const float*)d_in[14];
    kp.Wout  = (const float*)d_in[15];
    kp.bout  = (const float*)d_in[16];
    kp.out   = (float*)d_out;

    unsigned long long* hist = (unsigned long long*)d_ws;   // 19*2048*64 (8B each)
    float* Wef  = (float*)(hist + 19 * N_AG * 64);          // 4096
    int*   need = (int*)(Wef + 4096);                       // 19*2048
    int*   mcnt = need + 19 * N_AG;                         // 20*2048
    int*   midx = mcnt + STEPS * N_AG;                      // 20*2048*CAP
    int*   flags = midx + STEPS * N_AG * CAP;               // 32

    kp.hist = hist; kp.Wef = Wef; kp.need = need; kp.mcnt = mcnt;
    kp.midx = midx; kp.flags = flags;

    k_all<<<NSRV + 128, 512, 0, stream>>>(kp);
}

// Round 15
// 184.889 us; speedup vs baseline: 1.1464x; 1.0057x over previous
//
#include <hip/hip_runtime.h>
#include <math.h>

// ---------------------------------------------------------------------------
// SocialLstm: T=24, N=2048, INPUT_DIM=2, HIDDEN=64, MEDIATE=128, SOCIAL=64,
// OUT_DIM=2, N_SIZE=2, CELL=0.3, T_obs=9, T_pred=19, WIN=9.
//
// R15 = R14 (best: k_all 106.3us / 186.0 total) + two extensions of the
// validated poll-prefetch lever:
//  1. prefetch issued at the TOP of the step (before B1, not after bar1):
//     first-partner address needs only LDS-stable sMidx/sCnt -> overlap
//     window grows from ~300cyc (C1) to ~600+cyc (B1+bar1+C1), covering
//     most of the ~900cyc coherent-point round trip.
//  2. partner 1 prefetched too (cnt>=2, ~13% of matched agents, previously
//     a second fully-exposed round trip). Straight-line issue + sequential
//     validation; accumulation order preserved -> bit-identical output.
// MFMA hi/lo bf16 split (ZhWh+ZlWh+ZhWl) verified R3-R14, absmax ~2e-3.
// ---------------------------------------------------------------------------

#define N_AG   2048
#define STEPS  20
#define CAP    12
#define NSRV   21
#define MAGIC  0x13572468

typedef short short8 __attribute__((ext_vector_type(8)));
typedef float f32x4  __attribute__((ext_vector_type(4)));
union FU { uint4 q; short8 v; };

__device__ __forceinline__ unsigned short bf16rne(float x) {
    unsigned u = __float_as_uint(x);
    unsigned r = (u + 0x7fff + ((u >> 16) & 1)) >> 16;
    return (unsigned short)r;
}

__device__ __forceinline__ int khash(int k) {
    return (int)(((unsigned)k * 2654435761u) >> 21);   // 11-bit bucket
}

__device__ __forceinline__ float fsigm(float x) {
    return __builtin_amdgcn_rcpf(1.f + __expf(-x));
}
__device__ __forceinline__ float ftanh(float x) {
    float e = __expf(2.f * x);
    return 1.f - 2.f * __builtin_amdgcn_rcpf(e + 1.f);
}

// LDS-only barrier (no vmcnt drain; global exchanges use the tag protocol).
__device__ __forceinline__ void bar_lds() {
    asm volatile("s_waitcnt lgkmcnt(0)\n\ts_barrier" ::: "memory");
}

__device__ __forceinline__ void ast(int* p_, int v) {
    __hip_atomic_store(p_, v, __ATOMIC_RELAXED, __HIP_MEMORY_SCOPE_AGENT);
}
__device__ __forceinline__ void astf(float* p_, float v) {
    __hip_atomic_store(p_, v, __ATOMIC_RELAXED, __HIP_MEMORY_SCOPE_AGENT);
}
__device__ __forceinline__ unsigned long long aldu64(const unsigned long long* p_) {
    return __hip_atomic_load(p_, __ATOMIC_RELAXED, __HIP_MEMORY_SCOPE_AGENT);
}

struct KP {
    const float *X, *masks, *h_in, *c_in;
    const float *Win, *bin, *Wsoc, *bsoc, *Wih, *Whh, *bih, *bhh, *Wout, *bout;
    float *Wef;
    int *mcnt, *midx, *need, *flags;
    float *out;
    unsigned long long *hist;    // 19 slices x [2048][64] of (tag<<32|f32bits)
};

__global__ __launch_bounds__(512, 1) void k_all(KP p)
{
    // ---- persist LDS ----
    __shared__ __align__(16) uint4 zshq[544];     // frag slot s5*17 + m
    __shared__ __align__(16) uint4 zslq[544];
    __shared__ float gbuf[16][258];
    __shared__ float cvs[16][64];
    __shared__ float hs[16][68];
    __shared__ float sWefP[64 * 65];
    __shared__ float2 sWinP[16 * 17];
    __shared__ float sBinP[16 * 9];
    __shared__ float sX[11][16][2];
    __shared__ float sMask[STEPS][16];
    __shared__ int   sCnt[STEPS][16];
    __shared__ int   sNeed[19][16];
    __shared__ int   sMidx[STEPS][16][CAP];
    __shared__ float sBsoc[64], sBc[256], sWout[128], sBout[2];
    __shared__ uint4 sE0h[8], sE0l[8];
    __shared__ float olocal[2][16][2];
    // ---- service LDS ----
    __shared__ int kk[N_AG];
    __shared__ int head[N_AG];
    __shared__ int nxt[N_AG];
    __shared__ float red[512];

    const int tid = threadIdx.x;
    const int bxg = blockIdx.x;

    // =====================================================================
    // SERVICE BLOCKS 0..20  (unchanged from R11/R14)
    // =====================================================================
    if (bxg < NSRV) {
        const int sb = bxg;
        {   // out-tail zero slice (frames 20..23 = 16384 floats)
            int lo = sb * 780;
            int hi = (sb == NSRV - 1) ? 16384 : lo + 780;
            for (int i = lo + tid; i < hi; i += 512)
                p.out[20 * N_AG * 2 + i] = 0.f;
        }
        if (sb == 20) {           // We fold
            for (int i = tid; i < 4096; i += 512) {
                int s = i >> 6, k = i & 63;
                float a = 0.f;
                #pragma unroll
                for (int w = 0; w < 9; w++) a += p.Wsoc[s * 576 + w * 64 + k];
                astf(&p.Wef[i], a);
            }
            __syncthreads();
            if (tid == 0) ast(&p.flags[20], MAGIC);
            return;
        }

        const int t = sb;
        const float* Xt = p.X + t * N_AG * 2;

        float mnx = 1e30f, mny = 1e30f;
        for (int i = tid; i < N_AG; i += 512) {
            mnx = fminf(mnx, Xt[2 * i]);
            mny = fminf(mny, Xt[2 * i + 1]);
        }
        red[tid] = mnx; __syncthreads();
        for (int s = 256; s > 0; s >>= 1) { if (tid < s) red[tid] = fminf(red[tid], red[tid + s]); __syncthreads(); }
        float ltx = red[0]; __syncthreads();
        red[tid] = mny; __syncthreads();
        for (int s = 256; s > 0; s >>= 1) { if (tid < s) red[tid] = fminf(red[tid], red[tid + s]); __syncthreads(); }
        float lty = red[0]; __syncthreads();
        ltx -= 1.2f;   // margin = 2*N_SIZE*CELL
        lty -= 1.2f;

        for (int i = tid; i < N_AG; i += 512) {
            float m = p.masks[t * N_AG + i];
            int px = (int)floorf((Xt[2 * i]     - ltx) / 0.3f);
            int py = (int)floorf((Xt[2 * i + 1] - lty) / 0.3f);
            int im = (int)m;
            px *= im; py *= im;
            kk[i] = px * 65536 + py;    // masked -> 0; real agents px,py >= 4
            head[i] = -1;
            if (t >= 1) ast(&p.need[(t - 1) * N_AG + i], 0);
        }
        __syncthreads();
        for (int j = tid; j < N_AG; j += 512) {
            int kj = kk[j];
            if (kj != 0) nxt[j] = atomicExch(&head[khash(kj)], j);
        }
        __syncthreads();
        for (int i = tid; i < N_AG; i += 512) {
            int ki = kk[i];
            int cnt = 0;
            int base = (t * N_AG + i) * CAP;
            if (ki != 0) {
                int tkey = ki - 65537;
                int lst[CAP];
                for (int j = head[khash(tkey)]; j >= 0; j = nxt[j]) {
                    if (kk[j] == tkey) { if (cnt < CAP) lst[cnt] = j; cnt++; }
                }
                if (cnt > CAP) cnt = CAP;
                for (int a = 1; a < cnt; a++) {       // ascending j = ref order
                    int v = lst[a]; int b = a - 1;
                    while (b >= 0 && lst[b] > v) { lst[b + 1] = lst[b]; b--; }
                    lst[b + 1] = v;
                }
                for (int a = 0; a < cnt; a++) {
                    ast(&p.midx[base + a], lst[a]);
                    if (t >= 1) ast(&p.need[(t - 1) * N_AG + lst[a]], 1);
                }
            }
            ast(&p.mcnt[t * N_AG + i], cnt);
        }
        __syncthreads();          // all waves' table stores acked
        if (tid == 0) ast(&p.flags[t], MAGIC);
        return;
    }

    // =====================================================================
    // PERSIST BLOCKS 21..148  (R11 structure + R14/R15 poll prefetch)
    // =====================================================================
    const int bx    = bxg - NSRV;
    const int wbase = bx * 16;
    const int wv    = tid >> 6, lane = tid & 63;
    const int mA    = lane & 15, quad = lane >> 4;
    const int nt0   = 2 * wv;

    // ---- prologue part A (independent of service tables) ----
    if (tid < 256) sBc[tid] = p.bih[tid] + p.bhh[tid];
    if (tid < 128) {
        sWout[tid] = p.Wout[tid];
        int c = tid;
        sWinP[(c >> 3) * 17 + (c & 7)] = make_float2(p.Win[2 * c], p.Win[2 * c + 1]);
        sBinP[(c >> 3) * 9 + (c & 7)] = p.bin[c];
    }
    if (tid < 64) sBsoc[tid] = p.bsoc[tid];
    if (tid < 2)  sBout[tid] = p.bout[tid];
    if (tid < 8) {
        unsigned uh[4], ul[4];
        #pragma unroll
        for (int w = 0; w < 4; w++) {
            float v0 = fmaxf(p.bsoc[tid * 8 + 2 * w], 0.f);
            float v1 = fmaxf(p.bsoc[tid * 8 + 2 * w + 1], 0.f);
            unsigned short h0 = bf16rne(v0), h1 = bf16rne(v1);
            float f0 = __uint_as_float(((unsigned)h0) << 16);
            float f1 = __uint_as_float(((unsigned)h1) << 16);
            unsigned short l0 = bf16rne(v0 - f0), l1 = bf16rne(v1 - f1);
            uh[w] = (unsigned)h0 | ((unsigned)h1 << 16);
            ul[w] = (unsigned)l0 | ((unsigned)l1 << 16);
        }
        sE0h[tid] = make_uint4(uh[0], uh[1], uh[2], uh[3]);
        sE0l[tid] = make_uint4(ul[0], ul[1], ul[2], ul[3]);
    }
    if (tid < 352) { int tt = tid / 32, r = tid % 32;
                     sX[tt][r >> 1][r & 1] = p.X[tt * (N_AG * 2) + (wbase + (r >> 1)) * 2 + (r & 1)]; }
    if (tid < 320) { int tt = tid / 16, m2 = tid % 16;
                     sMask[tt][m2] = p.masks[tt * N_AG + wbase + m2]; }

    // own h (LDS) + c (registers)
    float c0, c1;
    {
        int m0 = tid >> 6, h0i = tid & 63, m1 = m0 + 8;
        hs[m0][h0i] = p.h_in[(wbase + m0) * 64 + h0i];
        hs[m1][h0i] = p.h_in[(wbase + m1) * 64 + h0i];
        c0 = p.c_in[(wbase + m0) * 64 + h0i];
        c1 = p.c_in[(wbase + m1) * 64 + h0i];
    }

    // register-resident W fragments (hi/lo split), loaded once
    FU wh[2][8], wl[2][8];
    #pragma unroll
    for (int e = 0; e < 2; e++) {
        int g = (nt0 + e) * 16 + mA;
        #pragma unroll
        for (int kt = 0; kt < 8; kt++) {
            int k0 = kt * 32 + quad * 8;        // 8-run never crosses 192 boundary
            const float* src = (k0 < 192) ? (p.Wih + g * 192 + k0)
                                          : (p.Whh + g * 64 + (k0 - 192));
            unsigned uh[4], ul[4];
            #pragma unroll
            for (int w = 0; w < 4; w++) {
                float a = src[2 * w], b = src[2 * w + 1];
                unsigned short ha = bf16rne(a), hb = bf16rne(b);
                float fa = __uint_as_float(((unsigned)ha) << 16);
                float fb = __uint_as_float(((unsigned)hb) << 16);
                unsigned short la = bf16rne(a - fa), lb = bf16rne(b - fb);
                uh[w] = (unsigned)ha | ((unsigned)hb << 16);
                ul[w] = (unsigned)la | ((unsigned)lb << 16);
            }
            wh[e][kt].q = make_uint4(uh[0], uh[1], uh[2], uh[3]);
            wl[e][kt].q = make_uint4(ul[0], ul[1], ul[2], ul[3]);
        }
    }

    // ---- wait for service flags (overlaps service work with prologue) ----
    if (tid < NSRV) {
        while (__hip_atomic_load(&p.flags[tid], __ATOMIC_RELAXED,
                                 __HIP_MEMORY_SCOPE_AGENT) != MAGIC) { }
    }
    __syncthreads();

    // ---- prologue part B: service tables (first-touch plain loads) ----
    if (tid < 320) { int tt = tid / 16, m2 = tid % 16;
                     sCnt[tt][m2] = p.mcnt[tt * N_AG + wbase + m2]; }
    if (tid < 304) { int s = tid / 16, m2 = tid % 16;
                     sNeed[s][m2] = p.need[s * N_AG + wbase + m2]; }
    for (int i = tid; i < 4096; i += 512) sWefP[(i >> 6) * 65 + (i & 63)] = p.Wef[i];
    for (int i = tid; i < STEPS * 16 * CAP; i += 512) {
        int tt = i / (16 * CAP), r = i % (16 * CAP), m2 = r / CAP, n = r % CAP;
        sMidx[tt][m2][n] = p.midx[(tt * N_AG + wbase + m2) * CAP + n];
    }
    __syncthreads();

    // =================== recurrence (R11 structure) ===================
    #pragma unroll 1
    for (int t = 0; t < STEPS; t++) {
        const int m5 = tid >> 5, s5 = tid & 31;
        const int cnt5 = sCnt[t][m5];

        // ---- A''-issue at step TOP: partners 0 and 1, no wait (t>0) ----
        // (addresses need only LDS-stable sMidx/sCnt; loads stay in flight
        //  through B1 + bar1 + C1 -> ~600+cyc of the round trip overlapped)
        const unsigned long long* hb = p.hist + (size_t)(t - 1) * (N_AG * 64);
        unsigned long long pw0 = 0, pw1 = 0, qw0 = 0, qw1 = 0;
        int rfirst = -1, rsecond = -1;
        if (cnt5 > 0 && t > 0) {
            rfirst = sMidx[t][m5][0];
            pw0 = aldu64(&hb[rfirst * 64 + s5]);
            pw1 = aldu64(&hb[rfirst * 64 + s5 + 32]);
            if (cnt5 > 1) {
                rsecond = sMidx[t][m5][1];
                qw0 = aldu64(&hb[rsecond * 64 + s5]);
                qw1 = aldu64(&hb[rsecond * 64 + s5 + 32]);
            }
        }

        // ---- B1: r-frags, h-frags, const-e-frags for unmatched ----
        {
            if (s5 < 16) {                       // r-cols c = s5*8 + j
                float px, py;
                if (t <= 10) { px = sX[t][m5][0];         py = sX[t][m5][1]; }
                else         { px = olocal[t & 1][m5][0]; py = olocal[t & 1][m5][1]; }
                float v[8];
                #pragma unroll
                for (int j = 0; j < 8; j++) {
                    float2 w2 = sWinP[s5 * 17 + j];
                    v[j] = fmaxf(w2.x * px + w2.y * py + sBinP[s5 * 9 + j], 0.f);
                }
                unsigned uh[4], ul[4];
                #pragma unroll
                for (int w = 0; w < 4; w++) {
                    float v0 = v[2 * w], v1 = v[2 * w + 1];
                    unsigned short h0 = bf16rne(v0), h1 = bf16rne(v1);
                    float f0 = __uint_as_float(((unsigned)h0) << 16);
                    float f1 = __uint_as_float(((unsigned)h1) << 16);
                    unsigned short l0 = bf16rne(v0 - f0), l1 = bf16rne(v1 - f1);
                    uh[w] = (unsigned)h0 | ((unsigned)h1 << 16);
                    ul[w] = (unsigned)l0 | ((unsigned)l1 << 16);
                }
                zshq[s5 * 17 + m5] = make_uint4(uh[0], uh[1], uh[2], uh[3]);
                zslq[s5 * 17 + m5] = make_uint4(ul[0], ul[1], ul[2], ul[3]);
            } else if (s5 < 24) {                // e-cols: const frag if unmatched
                if (cnt5 == 0) {
                    zshq[s5 * 17 + m5] = sE0h[s5 - 16];
                    zslq[s5 * 17 + m5] = sE0l[s5 - 16];
                }
            } else {                             // h-cols
                float v[8];
                #pragma unroll
                for (int j = 0; j < 8; j++) v[j] = hs[m5][(s5 - 24) * 8 + j];
                unsigned uh[4], ul[4];
                #pragma unroll
                for (int w = 0; w < 4; w++) {
                    float v0 = v[2 * w], v1 = v[2 * w + 1];
                    unsigned short h0 = bf16rne(v0), h1 = bf16rne(v1);
                    float f0 = __uint_as_float(((unsigned)h0) << 16);
                    float f1 = __uint_as_float(((unsigned)h1) << 16);
                    unsigned short l0 = bf16rne(v0 - f0), l1 = bf16rne(v1 - f1);
                    uh[w] = (unsigned)h0 | ((unsigned)h1 << 16);
                    ul[w] = (unsigned)l0 | ((unsigned)l1 << 16);
                }
                zshq[s5 * 17 + m5] = make_uint4(uh[0], uh[1], uh[2], uh[3]);
                zslq[s5 * 17 + m5] = make_uint4(ul[0], ul[1], ul[2], ul[3]);
            }
        }
        bar_lds();   // bar1: r/h/const-e frags visible

        // ---- C1: r/h k-tiles (0..3, 6, 7) — overlaps the poll round trip --
        f32x4 a0v = {0.f, 0.f, 0.f, 0.f};
        f32x4 a1v = {0.f, 0.f, 0.f, 0.f};
        #pragma unroll
        for (int u = 0; u < 6; u++) {
            const int kt = (u < 4) ? u : u + 2;   // 0,1,2,3,6,7
            int fi = (kt * 4 + quad) * 17 + mA;
            FU az, bz;
            az.q = zshq[fi];
            bz.q = zslq[fi];
            a0v = __builtin_amdgcn_mfma_f32_16x16x32_bf16(az.v, wh[0][kt].v, a0v, 0, 0, 0);
            a1v = __builtin_amdgcn_mfma_f32_16x16x32_bf16(az.v, wh[1][kt].v, a1v, 0, 0, 0);
            a0v = __builtin_amdgcn_mfma_f32_16x16x32_bf16(bz.v, wh[0][kt].v, a0v, 0, 0, 0);
            a1v = __builtin_amdgcn_mfma_f32_16x16x32_bf16(bz.v, wh[1][kt].v, a1v, 0, 0, 0);
            a0v = __builtin_amdgcn_mfma_f32_16x16x32_bf16(az.v, wl[0][kt].v, a0v, 0, 0, 0);
            a1v = __builtin_amdgcn_mfma_f32_16x16x32_bf16(az.v, wl[1][kt].v, a1v, 0, 0, 0);
        }

        // ---- A''-complete: validate/gather + e-dot + shuffle-frag ----
        if (cnt5 > 0) {
            float a0 = 0.f, a1 = 0.f;
            if (t == 0) {
                for (int n = 0; n < cnt5; n++) {
                    int r = sMidx[0][m5][n];
                    a0 += p.h_in[r * 64 + s5];
                    a1 += p.h_in[r * 64 + s5 + 32];
                }
            } else {
                const unsigned tagw = (unsigned)t;
                // partner 0: prefetched; retry only if stale
                while ((unsigned)(pw0 >> 32) != tagw || (unsigned)(pw1 >> 32) != tagw) {
                    pw0 = aldu64(&hb[rfirst * 64 + s5]);
                    pw1 = aldu64(&hb[rfirst * 64 + s5 + 32]);
                }
                a0 += __uint_as_float((unsigned)pw0);
                a1 += __uint_as_float((unsigned)pw1);
                if (cnt5 > 1) {
                    // partner 1: prefetched; retry only if stale
                    while ((unsigned)(qw0 >> 32) != tagw || (unsigned)(qw1 >> 32) != tagw) {
                        qw0 = aldu64(&hb[rsecond * 64 + s5]);
                        qw1 = aldu64(&hb[rsecond * 64 + s5 + 32]);
                    }
                    a0 += __uint_as_float((unsigned)qw0);
                    a1 += __uint_as_float((unsigned)qw1);
                    for (int n = 2; n < cnt5; n++) {
                        int r = sMidx[t][m5][n];
                        unsigned long long w0, w1;
                        do {
                            w0 = aldu64(&hb[r * 64 + s5]);
                            w1 = aldu64(&hb[r * 64 + s5 + 32]);
                        } while ((unsigned)(w0 >> 32) != tagw || (unsigned)(w1 >> 32) != tagw);
                        a0 += __uint_as_float((unsigned)w0);
                        a1 += __uint_as_float((unsigned)w1);
                    }
                }
            }
            cvs[m5][s5] = a0; cvs[m5][s5 + 32] = a1;
            float acc0 = sBsoc[s5], acc1 = sBsoc[s5 + 32];
            const float* w0p = &sWefP[s5 * 65];
            const float* w1p = &sWefP[(s5 + 32) * 65];
            for (int k = 0; k < 64; k++) {
                float cv = cvs[m5][k];
                acc0 += cv * w0p[k];
                acc1 += cv * w1p[k];
            }
            acc0 = fmaxf(acc0, 0.f);
            acc1 = fmaxf(acc1, 0.f);
            const int base = (m5 & 1) * 32;
            float v[8];
            #pragma unroll
            for (int jj = 0; jj < 8; jj++) {
                int c = s5 * 8 + jj;             // meaningful for s5<8
                int srcl = base + ((c < 32 ? c : c - 32) & 31);
                float va = __shfl(acc0, srcl, 64);
                float vb = __shfl(acc1, srcl, 64);
                v[jj] = (c < 32) ? va : vb;
            }
            if (s5 < 8) {
                unsigned uh[4], ul[4];
                #pragma unroll
                for (int w = 0; w < 4; w++) {
                    float v0 = v[2 * w], v1 = v[2 * w + 1];
                    unsigned short h0 = bf16rne(v0), h1 = bf16rne(v1);
                    float f0 = __uint_as_float(((unsigned)h0) << 16);
                    float f1 = __uint_as_float(((unsigned)h1) << 16);
                    unsigned short l0 = bf16rne(v0 - f0), l1 = bf16rne(v1 - f1);
                    uh[w] = (unsigned)h0 | ((unsigned)h1 << 16);
                    ul[w] = (unsigned)l0 | ((unsigned)l1 << 16);
                }
                zshq[(16 + s5) * 17 + m5] = make_uint4(uh[0], uh[1], uh[2], uh[3]);
                zslq[(16 + s5) * 17 + m5] = make_uint4(ul[0], ul[1], ul[2], ul[3]);
            }
        }
        bar_lds();   // bar2: e-frags visible, all C1 issued

        // ---- C2: e k-tiles (4, 5); write gbuf ----
        #pragma unroll
        for (int kt = 4; kt <= 5; kt++) {
            int fi = (kt * 4 + quad) * 17 + mA;
            FU az, bz;
            az.q = zshq[fi];
            bz.q = zslq[fi];
            a0v = __builtin_amdgcn_mfma_f32_16x16x32_bf16(az.v, wh[0][kt].v, a0v, 0, 0, 0);
            a1v = __builtin_amdgcn_mfma_f32_16x16x32_bf16(az.v, wh[1][kt].v, a1v, 0, 0, 0);
            a0v = __builtin_amdgcn_mfma_f32_16x16x32_bf16(bz.v, wh[0][kt].v, a0v, 0, 0, 0);
            a1v = __builtin_amdgcn_mfma_f32_16x16x32_bf16(bz.v, wh[1][kt].v, a1v, 0, 0, 0);
            a0v = __builtin_amdgcn_mfma_f32_16x16x32_bf16(az.v, wl[0][kt].v, a0v, 0, 0, 0);
            a1v = __builtin_amdgcn_mfma_f32_16x16x32_bf16(az.v, wl[1][kt].v, a1v, 0, 0, 0);
        }
        #pragma unroll
        for (int r = 0; r < 4; r++) {
            int row = quad * 4 + r;           // agent slot
            gbuf[row][nt0 * 16 + mA]       = a0v[r];
            gbuf[row][(nt0 + 1) * 16 + mA] = a1v[r];
        }
        bar_lds();   // bar3: gbuf visible

        // ---- D: LSTM; tagged publish of needed h; E: out reduce ----
        {
            int m0 = tid >> 6, hid = tid & 63, m1 = m0 + 8;
            float hn0, hn1;
            {
                float gi = gbuf[m0][hid]       + sBc[hid];
                float gf = gbuf[m0][64 + hid]  + sBc[64 + hid];
                float gR = gbuf[m0][128 + hid] + sBc[128 + hid];
                float go = gbuf[m0][192 + hid] + sBc[192 + hid];
                float cn = fsigm(gf) * c0 + fsigm(gi) * ftanh(gR);
                hn0 = fsigm(go) * ftanh(cn);
                c0 = cn;
                hs[m0][hid] = hn0;
            }
            {
                float gi = gbuf[m1][hid]       + sBc[hid];
                float gf = gbuf[m1][64 + hid]  + sBc[64 + hid];
                float gR = gbuf[m1][128 + hid] + sBc[128 + hid];
                float go = gbuf[m1][192 + hid] + sBc[192 + hid];
                float cn = fsigm(gf) * c1 + fsigm(gi) * ftanh(gR);
                hn1 = fsigm(go) * ftanh(cn);
                c1 = cn;
                hs[m1][hid] = hn1;
            }
            if (t <= 18) {
                unsigned long long* hp = p.hist + (size_t)t * (N_AG * 64);
                unsigned long long tg = ((unsigned long long)(t + 1)) << 32;
                if (sNeed[t][m0])
                    __hip_atomic_store(&hp[(wbase + m0) * 64 + hid],
                                       tg | (unsigned long long)__float_as_uint(hn0),
                                       __ATOMIC_RELAXED, __HIP_MEMORY_SCOPE_AGENT);
                if (sNeed[t][m1])
                    __hip_atomic_store(&hp[(wbase + m1) * 64 + hid],
                                       tg | (unsigned long long)__float_as_uint(hn1),
                                       __ATOMIC_RELAXED, __HIP_MEMORY_SCOPE_AGENT);
            }

            float w0 = sWout[hid], w1 = sWout[64 + hid];
            float p00 = hn0 * w0, p01 = hn0 * w1;
            float p10 = hn1 * w0, p11 = hn1 * w1;
            #pragma unroll
            for (int off = 32; off >= 1; off >>= 1) {
                p00 += __shfl_xor(p00, off);
                p01 += __shfl_xor(p01, off);
                p10 += __shfl_xor(p10, off);
                p11 += __shfl_xor(p11, off);
            }
            if (hid == 0) {
                float mk0 = sMask[t][m0], mk1 = sMask[t][m1];
                float o00 = (p00 + sBout[0]) * mk0, o01 = (p01 + sBout[1]) * mk0;
                float o10 = (p10 + sBout[0]) * mk1, o11 = (p11 + sBout[1]) * mk1;
                p.out[(t * N_AG + wbase + m0) * 2 + 0] = o00;
                p.out[(t * N_AG + wbase + m0) * 2 + 1] = o01;
                p.out[(t * N_AG + wbase + m1) * 2 + 0] = o10;
                p.out[(t * N_AG + wbase + m1) * 2 + 1] = o11;
                olocal[t & 1][m0][0] = o00; olocal[t & 1][m0][1] = o01;
                olocal[t & 1][m1][0] = o10; olocal[t & 1][m1][1] = o11;
            }
        }
        bar_lds();   // bar4: hs + olocal stable before next step
    }
}

// ---------------------------------------------------------------------------
extern "C" void kernel_launch(void* const* d_in, const int* in_sizes, int n_in,
                              void* d_out, int out_size, void* d_ws, size_t ws_size,
                              hipStream_t stream)
{
    KP kp;
    kp.X     = (const float*)d_in[0];
    kp.masks = (const float*)d_in[1];
    kp.h_in  = (const float*)d_in[2];
    kp.c_in  = (const float*)d_in[3];
    // d_in[4] = Y (unused), d_in[5] = T_obs (=9), d_in[6] = T_pred (=19)
    kp.Win   = (const float*)d_in[7];
    kp.bin   = (const float*)d_in[8];
    kp.Wsoc  = (const float*)d_in[9];
    kp.bsoc  = (const float*)d_in[10];
    kp.Wih   = (const float*)d_in[11];
    kp.Whh   = (const float*)d_in[12];
    kp.bih   = (const float*)d_in[13];
    kp.bhh   = (const float*)d_in[14];
    kp.Wout  = (const float*)d_in[15];
    kp.bout  = (const float*)d_in[16];
    kp.out   = (float*)d_out;

    unsigned long long* hist = (unsigned long long*)d_ws;   // 19*2048*64 (8B each)
    float* Wef  = (float*)(hist + 19 * N_AG * 64);          // 4096
    int*   need = (int*)(Wef + 4096);                       // 19*2048
    int*   mcnt = need + 19 * N_AG;                         // 20*2048
    int*   midx = mcnt + STEPS * N_AG;                      // 20*2048*CAP
    int*   flags = midx + STEPS * N_AG * CAP;               // 32

    kp.hist = hist; kp.Wef = Wef; kp.need = need; kp.mcnt = mcnt;
    kp.midx = midx; kp.flags = flags;

    k_all<<<NSRV + 128, 512, 0, stream>>>(kp);
}

// Round 16
// 184.616 us; speedup vs baseline: 1.1481x; 1.0015x over previous
//
#include <hip/hip_runtime.h>
#include <math.h>

// ---------------------------------------------------------------------------
// SocialLstm: T=24, N=2048, INPUT_DIM=2, HIDDEN=64, MEDIATE=128, SOCIAL=64,
// OUT_DIM=2, N_SIZE=2, CELL=0.3, T_obs=9, T_pred=19, WIN=9.
//
// R16 = R15 (best: k_all 104.5us / 184.9 total) + 3-barrier step:
//  B1 folded into D as WAVE-LOCAL t+1 frag building (wave w owns agents
//  {w, w+8}: own hn regs, own hs rows via in-wave LDS ordering, own
//  post-butterfly out regs for the r-feedback; olocal LDS deleted,
//  out[t-1] double-buffered in registers). bar1 + B1 phase removed:
//  step = [prefetch][C1 + A''-complete][barA][C2][barB][D + t+1 frags][barC].
//  R9's version of this fold regressed, but R9 also had the poll serial at
//  D's end — that confound is gone (step-top prefetch since R15).
// MFMA hi/lo bf16 split (ZhWh+ZlWh+ZhWl) verified R3-R15, absmax ~2e-3.
// ---------------------------------------------------------------------------

#define N_AG   2048
#define STEPS  20
#define CAP    12
#define NSRV   21
#define MAGIC  0x13572468

typedef short short8 __attribute__((ext_vector_type(8)));
typedef float f32x4  __attribute__((ext_vector_type(4)));
union FU { uint4 q; short8 v; };

__device__ __forceinline__ unsigned short bf16rne(float x) {
    unsigned u = __float_as_uint(x);
    unsigned r = (u + 0x7fff + ((u >> 16) & 1)) >> 16;
    return (unsigned short)r;
}

__device__ __forceinline__ void pack8(const float* v, uint4& hq, uint4& lq) {
    unsigned uh[4], ul[4];
    #pragma unroll
    for (int w = 0; w < 4; w++) {
        float v0 = v[2 * w], v1 = v[2 * w + 1];
        unsigned short h0 = bf16rne(v0), h1 = bf16rne(v1);
        float f0 = __uint_as_float(((unsigned)h0) << 16);
        float f1 = __uint_as_float(((unsigned)h1) << 16);
        unsigned short l0 = bf16rne(v0 - f0), l1 = bf16rne(v1 - f1);
        uh[w] = (unsigned)h0 | ((unsigned)h1 << 16);
        ul[w] = (unsigned)l0 | ((unsigned)l1 << 16);
    }
    hq = make_uint4(uh[0], uh[1], uh[2], uh[3]);
    lq = make_uint4(ul[0], ul[1], ul[2], ul[3]);
}

__device__ __forceinline__ int khash(int k) {
    return (int)(((unsigned)k * 2654435761u) >> 21);   // 11-bit bucket
}

__device__ __forceinline__ float fsigm(float x) {
    return __builtin_amdgcn_rcpf(1.f + __expf(-x));
}
__device__ __forceinline__ float ftanh(float x) {
    float e = __expf(2.f * x);
    return 1.f - 2.f * __builtin_amdgcn_rcpf(e + 1.f);
}

// LDS-only barrier (no vmcnt drain; global exchanges use the tag protocol).
__device__ __forceinline__ void bar_lds() {
    asm volatile("s_waitcnt lgkmcnt(0)\n\ts_barrier" ::: "memory");
}

__device__ __forceinline__ void ast(int* p_, int v) {
    __hip_atomic_store(p_, v, __ATOMIC_RELAXED, __HIP_MEMORY_SCOPE_AGENT);
}
__device__ __forceinline__ void astf(float* p_, float v) {
    __hip_atomic_store(p_, v, __ATOMIC_RELAXED, __HIP_MEMORY_SCOPE_AGENT);
}
__device__ __forceinline__ unsigned long long aldu64(const unsigned long long* p_) {
    return __hip_atomic_load(p_, __ATOMIC_RELAXED, __HIP_MEMORY_SCOPE_AGENT);
}

struct KP {
    const float *X, *masks, *h_in, *c_in;
    const float *Win, *bin, *Wsoc, *bsoc, *Wih, *Whh, *bih, *bhh, *Wout, *bout;
    float *Wef;
    int *mcnt, *midx, *need, *flags;
    float *out;
    unsigned long long *hist;    // 19 slices x [2048][64] of (tag<<32|f32bits)
};

__global__ __launch_bounds__(512, 1) void k_all(KP p)
{
    // ---- persist LDS ----
    __shared__ __align__(16) uint4 zshq[544];     // frag slot s5*17 + m
    __shared__ __align__(16) uint4 zslq[544];
    __shared__ float gbuf[16][258];
    __shared__ float cvs[16][64];
    __shared__ float hs[16][68];                  // wave-local rows
    __shared__ float sWefP[64 * 65];
    __shared__ float2 sWinP[16 * 17];
    __shared__ float sBinP[16 * 9];
    __shared__ float sX[11][16][2];
    __shared__ float sMask[STEPS][16];
    __shared__ int   sCnt[STEPS][16];
    __shared__ int   sNeed[19][16];
    __shared__ int   sMidx[STEPS][16][CAP];
    __shared__ float sBsoc[64], sBc[256], sWout[128], sBout[2];
    __shared__ uint4 sE0h[8], sE0l[8];
    // ---- service LDS ----
    __shared__ int kk[N_AG];
    __shared__ int head[N_AG];
    __shared__ int nxt[N_AG];
    __shared__ float red[512];

    const int tid = threadIdx.x;
    const int bxg = blockIdx.x;

    // =====================================================================
    // SERVICE BLOCKS 0..20  (unchanged from R11/R14/R15)
    // =====================================================================
    if (bxg < NSRV) {
        const int sb = bxg;
        {   // out-tail zero slice (frames 20..23 = 16384 floats)
            int lo = sb * 780;
            int hi = (sb == NSRV - 1) ? 16384 : lo + 780;
            for (int i = lo + tid; i < hi; i += 512)
                p.out[20 * N_AG * 2 + i] = 0.f;
        }
        if (sb == 20) {           // We fold
            for (int i = tid; i < 4096; i += 512) {
                int s = i >> 6, k = i & 63;
                float a = 0.f;
                #pragma unroll
                for (int w = 0; w < 9; w++) a += p.Wsoc[s * 576 + w * 64 + k];
                astf(&p.Wef[i], a);
            }
            __syncthreads();
            if (tid == 0) ast(&p.flags[20], MAGIC);
            return;
        }

        const int t = sb;
        const float* Xt = p.X + t * N_AG * 2;

        float mnx = 1e30f, mny = 1e30f;
        for (int i = tid; i < N_AG; i += 512) {
            mnx = fminf(mnx, Xt[2 * i]);
            mny = fminf(mny, Xt[2 * i + 1]);
        }
        red[tid] = mnx; __syncthreads();
        for (int s = 256; s > 0; s >>= 1) { if (tid < s) red[tid] = fminf(red[tid], red[tid + s]); __syncthreads(); }
        float ltx = red[0]; __syncthreads();
        red[tid] = mny; __syncthreads();
        for (int s = 256; s > 0; s >>= 1) { if (tid < s) red[tid] = fminf(red[tid], red[tid + s]); __syncthreads(); }
        float lty = red[0]; __syncthreads();
        ltx -= 1.2f;   // margin = 2*N_SIZE*CELL
        lty -= 1.2f;

        for (int i = tid; i < N_AG; i += 512) {
            float m = p.masks[t * N_AG + i];
            int px = (int)floorf((Xt[2 * i]     - ltx) / 0.3f);
            int py = (int)floorf((Xt[2 * i + 1] - lty) / 0.3f);
            int im = (int)m;
            px *= im; py *= im;
            kk[i] = px * 65536 + py;    // masked -> 0; real agents px,py >= 4
            head[i] = -1;
            if (t >= 1) ast(&p.need[(t - 1) * N_AG + i], 0);
        }
        __syncthreads();
        for (int j = tid; j < N_AG; j += 512) {
            int kj = kk[j];
            if (kj != 0) nxt[j] = atomicExch(&head[khash(kj)], j);
        }
        __syncthreads();
        for (int i = tid; i < N_AG; i += 512) {
            int ki = kk[i];
            int cnt = 0;
            int base = (t * N_AG + i) * CAP;
            if (ki != 0) {
                int tkey = ki - 65537;
                int lst[CAP];
                for (int j = head[khash(tkey)]; j >= 0; j = nxt[j]) {
                    if (kk[j] == tkey) { if (cnt < CAP) lst[cnt] = j; cnt++; }
                }
                if (cnt > CAP) cnt = CAP;
                for (int a = 1; a < cnt; a++) {       // ascending j = ref order
                    int v = lst[a]; int b = a - 1;
                    while (b >= 0 && lst[b] > v) { lst[b + 1] = lst[b]; b--; }
                    lst[b + 1] = v;
                }
                for (int a = 0; a < cnt; a++) {
                    ast(&p.midx[base + a], lst[a]);
                    if (t >= 1) ast(&p.need[(t - 1) * N_AG + lst[a]], 1);
                }
            }
            ast(&p.mcnt[t * N_AG + i], cnt);
        }
        __syncthreads();          // all waves' table stores acked
        if (tid == 0) ast(&p.flags[t], MAGIC);
        return;
    }

    // =====================================================================
    // PERSIST BLOCKS 21..148  (3-barrier step)
    // =====================================================================
    const int bx    = bxg - NSRV;
    const int wbase = bx * 16;
    const int wv    = tid >> 6, lane = tid & 63;
    const int mA    = lane & 15, quad = lane >> 4;
    const int nt0   = 2 * wv;
    const int m0w   = wv, m1w = wv + 8;           // agents owned by this wave

    // ---- prologue part A (independent of service tables) ----
    if (tid < 256) sBc[tid] = p.bih[tid] + p.bhh[tid];
    if (tid < 128) {
        sWout[tid] = p.Wout[tid];
        int c = tid;
        sWinP[(c >> 3) * 17 + (c & 7)] = make_float2(p.Win[2 * c], p.Win[2 * c + 1]);
        sBinP[(c >> 3) * 9 + (c & 7)] = p.bin[c];
    }
    if (tid < 64) sBsoc[tid] = p.bsoc[tid];
    if (tid < 2)  sBout[tid] = p.bout[tid];
    if (tid < 8) {
        float v[8];
        #pragma unroll
        for (int j = 0; j < 8; j++) v[j] = fmaxf(p.bsoc[tid * 8 + j], 0.f);
        pack8(v, sE0h[tid], sE0l[tid]);
    }
    if (tid < 352) { int tt = tid / 32, r = tid % 32;
                     sX[tt][r >> 1][r & 1] = p.X[tt * (N_AG * 2) + (wbase + (r >> 1)) * 2 + (r & 1)]; }
    if (tid < 320) { int tt = tid / 16, m2 = tid % 16;
                     sMask[tt][m2] = p.masks[tt * N_AG + wbase + m2]; }

    // own h (wave-local LDS rows) + c (registers)
    float c0, c1;
    {
        hs[m0w][lane] = p.h_in[(wbase + m0w) * 64 + lane];
        hs[m1w][lane] = p.h_in[(wbase + m1w) * 64 + lane];
        c0 = p.c_in[(wbase + m0w) * 64 + lane];
        c1 = p.c_in[(wbase + m1w) * 64 + lane];
    }

    // register-resident W fragments (hi/lo split), loaded once
    FU wh[2][8], wl[2][8];
    #pragma unroll
    for (int e = 0; e < 2; e++) {
        int g = (nt0 + e) * 16 + mA;
        #pragma unroll
        for (int kt = 0; kt < 8; kt++) {
            int k0 = kt * 32 + quad * 8;        // 8-run never crosses 192 boundary
            const float* src = (k0 < 192) ? (p.Wih + g * 192 + k0)
                                          : (p.Whh + g * 64 + (k0 - 192));
            float v[8];
            #pragma unroll
            for (int j = 0; j < 8; j++) v[j] = src[j];
            pack8(v, wh[e][kt].q, wl[e][kt].q);
        }
    }

    // ---- wait for service flags (overlaps service work with prologue) ----
    if (tid < NSRV) {
        while (__hip_atomic_load(&p.flags[tid], __ATOMIC_RELAXED,
                                 __HIP_MEMORY_SCOPE_AGENT) != MAGIC) { }
    }
    __syncthreads();

    // ---- prologue part B: service tables (first-touch plain loads) ----
    if (tid < 320) { int tt = tid / 16, m2 = tid % 16;
                     sCnt[tt][m2] = p.mcnt[tt * N_AG + wbase + m2]; }
    if (tid < 304) { int s = tid / 16, m2 = tid % 16;
                     sNeed[s][m2] = p.need[s * N_AG + wbase + m2]; }
    for (int i = tid; i < 4096; i += 512) sWefP[(i >> 6) * 65 + (i & 63)] = p.Wef[i];
    for (int i = tid; i < STEPS * 16 * CAP; i += 512) {
        int tt = i / (16 * CAP), r = i % (16 * CAP), m2 = r / CAP, n = r % CAP;
        sMidx[tt][m2][n] = p.midx[(tt * N_AG + wbase + m2) * CAP + n];
    }
    __syncthreads();

    // ---- prologue: wave-local t=0 frag build ----
    {
        if (lane < 32) {
            int a = lane & 1, s5r = lane >> 1;
            int m = a ? m1w : m0w;
            float px = sX[0][m][0], py = sX[0][m][1];
            float v[8];
            #pragma unroll
            for (int j = 0; j < 8; j++) {
                float2 w2 = sWinP[s5r * 17 + j];
                v[j] = fmaxf(w2.x * px + w2.y * py + sBinP[s5r * 9 + j], 0.f);
            }
            pack8(v, zshq[s5r * 17 + m], zslq[s5r * 17 + m]);
        } else if (lane < 48) {
            int idx = lane - 32, a = idx & 1, s58 = idx >> 1;
            int m = a ? m1w : m0w;
            float v[8];
            #pragma unroll
            for (int j = 0; j < 8; j++) v[j] = hs[m][s58 * 8 + j];
            pack8(v, zshq[(24 + s58) * 17 + m], zslq[(24 + s58) * 17 + m]);
        } else {
            int idx = lane - 48, a = idx & 1, s58 = idx >> 1;
            int m = a ? m1w : m0w;
            if (sCnt[0][m] == 0) {
                zshq[(16 + s58) * 17 + m] = sE0h[s58];
                zslq[(16 + s58) * 17 + m] = sE0l[s58];
            }
        }
    }
    bar_lds();   // t=0 frags visible

    float op0x = 0.f, op0y = 0.f, op1x = 0.f, op1y = 0.f;   // out[t-1] regs

    // =================== recurrence: 3 lgkm barriers/step ===================
    #pragma unroll 1
    for (int t = 0; t < STEPS; t++) {
        const int m5 = tid >> 5, s5 = tid & 31;
        const int cnt5 = sCnt[t][m5];

        // ---- A''-issue at step TOP: partners 0 and 1, no wait (t>0) ----
        const unsigned long long* hb = p.hist + (size_t)(t - 1) * (N_AG * 64);
        unsigned long long pw0 = 0, pw1 = 0, qw0 = 0, qw1 = 0;
        int rfirst = -1, rsecond = -1;
        if (cnt5 > 0 && t > 0) {
            rfirst = sMidx[t][m5][0];
            pw0 = aldu64(&hb[rfirst * 64 + s5]);
            pw1 = aldu64(&hb[rfirst * 64 + s5 + 32]);
            if (cnt5 > 1) {
                rsecond = sMidx[t][m5][1];
                qw0 = aldu64(&hb[rsecond * 64 + s5]);
                qw1 = aldu64(&hb[rsecond * 64 + s5 + 32]);
            }
        }

        // ---- C1: r/h k-tiles (0..3, 6, 7) — overlaps the poll round trip --
        f32x4 a0v = {0.f, 0.f, 0.f, 0.f};
        f32x4 a1v = {0.f, 0.f, 0.f, 0.f};
        #pragma unroll
        for (int u = 0; u < 6; u++) {
            const int kt = (u < 4) ? u : u + 2;   // 0,1,2,3,6,7
            int fi = (kt * 4 + quad) * 17 + mA;
            FU az, bz;
            az.q = zshq[fi];
            bz.q = zslq[fi];
            a0v = __builtin_amdgcn_mfma_f32_16x16x32_bf16(az.v, wh[0][kt].v, a0v, 0, 0, 0);
            a1v = __builtin_amdgcn_mfma_f32_16x16x32_bf16(az.v, wh[1][kt].v, a1v, 0, 0, 0);
            a0v = __builtin_amdgcn_mfma_f32_16x16x32_bf16(bz.v, wh[0][kt].v, a0v, 0, 0, 0);
            a1v = __builtin_amdgcn_mfma_f32_16x16x32_bf16(bz.v, wh[1][kt].v, a1v, 0, 0, 0);
            a0v = __builtin_amdgcn_mfma_f32_16x16x32_bf16(az.v, wl[0][kt].v, a0v, 0, 0, 0);
            a1v = __builtin_amdgcn_mfma_f32_16x16x32_bf16(az.v, wl[1][kt].v, a1v, 0, 0, 0);
        }

        // ---- A''-complete: validate/gather + e-dot + shuffle-frag ----
        if (cnt5 > 0) {
            float a0 = 0.f, a1 = 0.f;
            if (t == 0) {
                for (int n = 0; n < cnt5; n++) {
                    int r = sMidx[0][m5][n];
                    a0 += p.h_in[r * 64 + s5];
                    a1 += p.h_in[r * 64 + s5 + 32];
                }
            } else {
                const unsigned tagw = (unsigned)t;
                while ((unsigned)(pw0 >> 32) != tagw || (unsigned)(pw1 >> 32) != tagw) {
                    pw0 = aldu64(&hb[rfirst * 64 + s5]);
                    pw1 = aldu64(&hb[rfirst * 64 + s5 + 32]);
                }
                a0 += __uint_as_float((unsigned)pw0);
                a1 += __uint_as_float((unsigned)pw1);
                if (cnt5 > 1) {
                    while ((unsigned)(qw0 >> 32) != tagw || (unsigned)(qw1 >> 32) != tagw) {
                        qw0 = aldu64(&hb[rsecond * 64 + s5]);
                        qw1 = aldu64(&hb[rsecond * 64 + s5 + 32]);
                    }
                    a0 += __uint_as_float((unsigned)qw0);
                    a1 += __uint_as_float((unsigned)qw1);
                    for (int n = 2; n < cnt5; n++) {
                        int r = sMidx[t][m5][n];
                        unsigned long long w0, w1;
                        do {
                            w0 = aldu64(&hb[r * 64 + s5]);
                            w1 = aldu64(&hb[r * 64 + s5 + 32]);
                        } while ((unsigned)(w0 >> 32) != tagw || (unsigned)(w1 >> 32) != tagw);
                        a0 += __uint_as_float((unsigned)w0);
                        a1 += __uint_as_float((unsigned)w1);
                    }
                }
            }
            cvs[m5][s5] = a0; cvs[m5][s5 + 32] = a1;
            float acc0 = sBsoc[s5], acc1 = sBsoc[s5 + 32];
            const float* w0p = &sWefP[s5 * 65];
            const float* w1p = &sWefP[(s5 + 32) * 65];
            for (int k = 0; k < 64; k++) {
                float cv = cvs[m5][k];
                acc0 += cv * w0p[k];
                acc1 += cv * w1p[k];
            }
            acc0 = fmaxf(acc0, 0.f);
            acc1 = fmaxf(acc1, 0.f);
            const int base = (m5 & 1) * 32;
            float v[8];
            #pragma unroll
            for (int jj = 0; jj < 8; jj++) {
                int c = s5 * 8 + jj;             // meaningful for s5<8
                int srcl = base + ((c < 32 ? c : c - 32) & 31);
                float va = __shfl(acc0, srcl, 64);
                float vb = __shfl(acc1, srcl, 64);
                v[jj] = (c < 32) ? va : vb;
            }
            if (s5 < 8)
                pack8(v, zshq[(16 + s5) * 17 + m5], zslq[(16 + s5) * 17 + m5]);
        }
        bar_lds();   // barA: e-frags visible, all C1 frag-reads drained

        // ---- C2: e k-tiles (4, 5); write gbuf ----
        #pragma unroll
        for (int kt = 4; kt <= 5; kt++) {
            int fi = (kt * 4 + quad) * 17 + mA;
            FU az, bz;
            az.q = zshq[fi];
            bz.q = zslq[fi];
            a0v = __builtin_amdgcn_mfma_f32_16x16x32_bf16(az.v, wh[0][kt].v, a0v, 0, 0, 0);
            a1v = __builtin_amdgcn_mfma_f32_16x16x32_bf16(az.v, wh[1][kt].v, a1v, 0, 0, 0);
            a0v = __builtin_amdgcn_mfma_f32_16x16x32_bf16(bz.v, wh[0][kt].v, a0v, 0, 0, 0);
            a1v = __builtin_amdgcn_mfma_f32_16x16x32_bf16(bz.v, wh[1][kt].v, a1v, 0, 0, 0);
            a0v = __builtin_amdgcn_mfma_f32_16x16x32_bf16(az.v, wl[0][kt].v, a0v, 0, 0, 0);
            a1v = __builtin_amdgcn_mfma_f32_16x16x32_bf16(az.v, wl[1][kt].v, a1v, 0, 0, 0);
        }
        #pragma unroll
        for (int r = 0; r < 4; r++) {
            int row = quad * 4 + r;           // agent slot
            gbuf[row][nt0 * 16 + mA]       = a0v[r];
            gbuf[row][(nt0 + 1) * 16 + mA] = a1v[r];
        }
        bar_lds();   // barB: gbuf visible, C2 e-frag reads drained

        // ---- D: LSTM; publish; out; wave-local t+1 frag build ----
        {
            const int hid = lane;
            float hn0, hn1;
            {
                float gi = gbuf[m0w][hid]       + sBc[hid];
                float gf = gbuf[m0w][64 + hid]  + sBc[64 + hid];
                float gR = gbuf[m0w][128 + hid] + sBc[128 + hid];
                float go = gbuf[m0w][192 + hid] + sBc[192 + hid];
                float cn = fsigm(gf) * c0 + fsigm(gi) * ftanh(gR);
                hn0 = fsigm(go) * ftanh(cn);
                c0 = cn;
                hs[m0w][hid] = hn0;
            }
            {
                float gi = gbuf[m1w][hid]       + sBc[hid];
                float gf = gbuf[m1w][64 + hid]  + sBc[64 + hid];
                float gR = gbuf[m1w][128 + hid] + sBc[128 + hid];
                float go = gbuf[m1w][192 + hid] + sBc[192 + hid];
                float cn = fsigm(gf) * c1 + fsigm(gi) * ftanh(gR);
                hn1 = fsigm(go) * ftanh(cn);
                c1 = cn;
                hs[m1w][hid] = hn1;
            }
            // publish EARLY (max slack before next step's top-of-step poll)
            if (t <= 18) {
                unsigned long long* hp = p.hist + (size_t)t * (N_AG * 64);
                unsigned long long tg = ((unsigned long long)(t + 1)) << 32;
                if (sNeed[t][m0w])
                    __hip_atomic_store(&hp[(wbase + m0w) * 64 + hid],
                                       tg | (unsigned long long)__float_as_uint(hn0),
                                       __ATOMIC_RELAXED, __HIP_MEMORY_SCOPE_AGENT);
                if (sNeed[t][m1w])
                    __hip_atomic_store(&hp[(wbase + m1w) * 64 + hid],
                                       tg | (unsigned long long)__float_as_uint(hn1),
                                       __ATOMIC_RELAXED, __HIP_MEMORY_SCOPE_AGENT);
            }

            // out: butterfly (all lanes end with all 4 sums)
            float w0 = sWout[hid], w1 = sWout[64 + hid];
            float p00 = hn0 * w0, p01 = hn0 * w1;
            float p10 = hn1 * w0, p11 = hn1 * w1;
            #pragma unroll
            for (int off = 32; off >= 1; off >>= 1) {
                p00 += __shfl_xor(p00, off);
                p01 += __shfl_xor(p01, off);
                p10 += __shfl_xor(p10, off);
                p11 += __shfl_xor(p11, off);
            }
            float mk0 = sMask[t][m0w], mk1 = sMask[t][m1w];
            float o00 = (p00 + sBout[0]) * mk0, o01 = (p01 + sBout[1]) * mk0;
            float o10 = (p10 + sBout[0]) * mk1, o11 = (p11 + sBout[1]) * mk1;
            if (lane == 0)
                *(float2*)&p.out[(t * N_AG + wbase + m0w) * 2] = make_float2(o00, o01);
            if (lane == 1)
                *(float2*)&p.out[(t * N_AG + wbase + m1w) * 2] = make_float2(o10, o11);

            // wave-local t+1 frag build (r uses out[tn-2] = out[t-1] = op*)
            if (t < STEPS - 1) {
                const int tn = t + 1;
                if (lane < 32) {
                    int a = lane & 1, s5r = lane >> 1;
                    int m = a ? m1w : m0w;
                    float px, py;
                    if (tn <= 10) { px = sX[tn][m][0]; py = sX[tn][m][1]; }
                    else          { px = a ? op1x : op0x;
                                    py = a ? op1y : op0y; }
                    float v[8];
                    #pragma unroll
                    for (int j = 0; j < 8; j++) {
                        float2 w2 = sWinP[s5r * 17 + j];
                        v[j] = fmaxf(w2.x * px + w2.y * py + sBinP[s5r * 9 + j], 0.f);
                    }
                    pack8(v, zshq[s5r * 17 + m], zslq[s5r * 17 + m]);
                } else if (lane < 48) {
                    int idx = lane - 32, a = idx & 1, s58 = idx >> 1;
                    int m = a ? m1w : m0w;
                    float v[8];
                    #pragma unroll
                    for (int j = 0; j < 8; j++) v[j] = hs[m][s58 * 8 + j];
                    pack8(v, zshq[(24 + s58) * 17 + m], zslq[(24 + s58) * 17 + m]);
                } else {
                    int idx = lane - 48, a = idx & 1, s58 = idx >> 1;
                    int m = a ? m1w : m0w;
                    if (sCnt[tn][m] == 0) {
                        zshq[(16 + s58) * 17 + m] = sE0h[s58];
                        zslq[(16 + s58) * 17 + m] = sE0l[s58];
                    }
                }
            }
            op0x = o00; op0y = o01;      // becomes out[t-1] for next iteration
            op1x = o10; op1y = o11;
        }
        bar_lds();   // barC: t+1 frags + hs stable before next step
    }
}

// ---------------------------------------------------------------------------
extern "C" void kernel_launch(void* const* d_in, const int* in_sizes, int n_in,
                              void* d_out, int out_size, void* d_ws, size_t ws_size,
                              hipStream_t stream)
{
    KP kp;
    kp.X     = (const float*)d_in[0];
    kp.masks = (const float*)d_in[1];
    kp.h_in  = (const float*)d_in[2];
    kp.c_in  = (const float*)d_in[3];
    // d_in[4] = Y (unused), d_in[5] = T_obs (=9), d_in[6] = T_pred (=19)
    kp.Win   = (const float*)d_in[7];
    kp.bin   = (const float*)d_in[8];
    kp.Wsoc  = (const float*)d_in[9];
    kp.bsoc  = (const float*)d_in[10];
    kp.Wih   = (const float*)d_in[11];
    kp.Whh   = (const float*)d_in[12];
    kp.bih   = (const float*)d_in[13];
    kp.bhh   = (const float*)d_in[14];
    kp.Wout  = (const float*)d_in[15];
    kp.bout  = (const float*)d_in[16];
    kp.out   = (float*)d_out;

    unsigned long long* hist = (unsigned long long*)d_ws;   // 19*2048*64 (8B each)
    float* Wef  = (float*)(hist + 19 * N_AG * 64);          // 4096
    int*   need = (int*)(Wef + 4096);                       // 19*2048
    int*   mcnt = need + 19 * N_AG;                         // 20*2048
    int*   midx = mcnt + STEPS * N_AG;                      // 20*2048*CAP
    int*   flags = midx + STEPS * N_AG * CAP;               // 32

    kp.hist = hist; kp.Wef = Wef; kp.need = need; kp.mcnt = mcnt;
    kp.midx = midx; kp.flags = flags;

    k_all<<<NSRV + 128, 512, 0, stream>>>(kp);
}